// Round 9
// baseline (393.448 us; speedup 1.0000x reference)
//
#include <hip/hip_runtime.h>
#include <hip/hip_bf16.h>

// LSDAN: 3-hop masked graph attention, N=4096, IN_F=256, H=128.
//  - masks of A^k via boolean bitset reachability (A is 0/1 with self-loops).
//  - e is rank-1: e[i][j]=lrelu(s1[i]+s2[j]); hopA shift M=lrelu(s1+gmax(s2)) (valid UB).
//  - hopB: fixed per-row shift M_i=||h_i||*max_j||W2h_j|| >= rowmax (Cauchy-Schwarz).
//  - Independent-wave K-split (R8): 16 rows/block, 4 waves own windows w,w+4,..;
//    zero barriers / zero cross-wave coupling in main loops; 4-way LDS combine.
//  - THIS ROUND:
//    (a) XCD<->hop affinity: blockIdx&7 ~ XCD; static bijective (hop,strip) map keeps
//        each XCD's B-operand streams (W2hb + 1-2 h_cm) inside its 4MB L2.
//    (b) batch-issue + hoisted B-operand loads: PV h_cm frags issued a phase early
//        (covered by S-MFMA/exp); hopA W1hTb frags batched before exp; bitset prefetch.

#define NN 4096
#define INF 256
#define HH 128
#define WPR 64
#define ALPHA_S 0.2f

typedef short bf16x8 __attribute__((ext_vector_type(8)));
typedef float f32x4 __attribute__((ext_vector_type(4)));

__device__ __forceinline__ float lrelu(float x) { return x > 0.f ? x : ALPHA_S * x; }
__device__ __forceinline__ unsigned short f2bf(float x) {
    __hip_bfloat16 h = __float2bfloat16(x);
    return *reinterpret_cast<unsigned short*>(&h);
}
__device__ __forceinline__ float bf2f(unsigned short u) {
    return __uint_as_float(((unsigned int)u) << 16);
}

// XCD-affine (hop,strip) map: 768 blocks, residue r=x&7 ~ XCD, k=x>>3 in [0,96).
// hop0: r0(96) r1(96) r2[k<64](64); hop1: r2[k>=64](32) r3(96) r4(96) r5[k<32](32);
// hop2: r5[k>=32](64) r6(96) r7(96).  Bijective onto 3x256 strips.
__device__ __forceinline__ void map_block(int x, int& hop, int& strip) {
    const int r = x & 7, k = x >> 3;
    if (r == 0) { hop = 0; strip = k; }
    else if (r == 1) { hop = 0; strip = 96 + k; }
    else if (r == 2) { if (k < 64) { hop = 0; strip = 192 + k; } else { hop = 1; strip = k - 64; } }
    else if (r == 3) { hop = 1; strip = 32 + k; }
    else if (r == 4) { hop = 1; strip = 128 + k; }
    else if (r == 5) { if (k < 32) { hop = 1; strip = 224 + k; } else { hop = 2; strip = k - 32; } }
    else if (r == 6) { hop = 2; strip = 64 + k; }
    else { hop = 2; strip = 160 + k; }
}

// ---- W1h = X@W1^T (f32 + bf16-transposed), W2h = X@W2^T (bf16 row-major) ----
__global__ __launch_bounds__(256) void k_xw(const float* __restrict__ X,
                                            const float* __restrict__ W1,
                                            const float* __restrict__ W2,
                                            float* __restrict__ W1h,
                                            unsigned short* __restrict__ W1hTb,
                                            unsigned short* __restrict__ W2hb) {
    __shared__ float xs[16 * INF];
    const int row0 = blockIdx.x * 16;
    const int t = threadIdx.x;
    for (int v = t; v < 16 * INF; v += 256) xs[v] = X[(size_t)row0 * INF + v];
    __syncthreads();
    const int c = t;
    const float* W = (c < HH) ? (W1 + (size_t)c * INF) : (W2 + (size_t)(c - HH) * INF);
    float acc[16];
#pragma unroll
    for (int r = 0; r < 16; ++r) acc[r] = 0.f;
    for (int k = 0; k < INF; ++k) {
        float wv = W[k];
#pragma unroll
        for (int r = 0; r < 16; ++r) acc[r] += xs[r * INF + k] * wv;
    }
    if (c < HH) {
        for (int r = 0; r < 16; ++r) {
            W1h[(size_t)(row0 + r) * HH + c] = acc[r];
            W1hTb[(size_t)c * NN + row0 + r] = f2bf(acc[r]);
        }
    } else {
        const int cc = c - HH;
        for (int r = 0; r < 16; ++r) W2hb[(size_t)(row0 + r) * HH + cc] = f2bf(acc[r]);
    }
}

// ---- s1 = W1h @ r[:H], s2 = W1h @ r[H:] ----
__global__ void k_s(const float* __restrict__ W1h, const float* __restrict__ r,
                    float* __restrict__ s1, float* __restrict__ s2) {
    int i = blockIdx.x * blockDim.x + threadIdx.x;
    if (i >= NN) return;
    float a = 0.f, b = 0.f;
    for (int h = 0; h < HH; ++h) {
        float v = W1h[(size_t)i * HH + h];
        a += v * r[h];
        b += v * r[HH + h];
    }
    s1[i] = a;
    s2[i] = b;
}

// ---- global max of 4096 floats ----
__global__ void k_gmax(const float* __restrict__ in, float* __restrict__ out) {
    __shared__ float red[256];
    const int t = threadIdx.x;
    float m = -3e38f;
    for (int i = t; i < NN; i += 256) m = fmaxf(m, in[i]);
    red[t] = m;
    __syncthreads();
    for (int off = 128; off; off >>= 1) {
        if (t < off) red[t] = fmaxf(red[t], red[t + off]);
        __syncthreads();
    }
    if (t == 0) out[0] = red[0];
}

// ---- W2h row norms ----
__global__ void k_wn(const unsigned short* __restrict__ W2hb, float* __restrict__ wnorm) {
    const int t = threadIdx.x;
    const int row = blockIdx.x * 16 + (t >> 4);
    const int sub = t & 15;
    bf16x8 v = *reinterpret_cast<const bf16x8*>(&W2hb[(size_t)row * HH + sub * 8]);
    float s = 0.f;
#pragma unroll
    for (int j = 0; j < 8; ++j) { float f = bf2f((unsigned short)v[j]); s += f * f; }
    s += __shfl_xor(s, 1, 64); s += __shfl_xor(s, 2, 64);
    s += __shfl_xor(s, 4, 64); s += __shfl_xor(s, 8, 64);
    if (sub == 0) wnorm[row] = sqrtf(s);
}

// ---- B1[i] bitset from A row i ----
__global__ void k_b1(const float* __restrict__ A, unsigned long long* __restrict__ B1) {
    const int wave = threadIdx.x >> 6;
    const int lane = threadIdx.x & 63;
    const int i = blockIdx.x * 4 + wave;
    for (int w = 0; w < WPR; ++w) {
        float a = A[(size_t)i * NN + w * 64 + lane];
        unsigned long long m = __ballot(a != 0.0f);
        if (lane == 0) B1[(size_t)i * WPR + w] = m;
    }
}

// ---- boolean matmul for reachability ----
__global__ void k_boolmm(const unsigned long long* __restrict__ srcbits,
                         const unsigned long long* __restrict__ mat,
                         unsigned long long* __restrict__ out) {
    const int wave = threadIdx.x >> 6;
    const int lane = threadIdx.x & 63;
    const int i = blockIdx.x * 4 + wave;
    unsigned long long myword = srcbits[(size_t)i * WPR + lane];
    unsigned long long acc = 0ull;
    for (int w = 0; w < WPR; ++w) {
        unsigned long long bits = __shfl(myword, w, 64);
        while (bits) {
            int b = __builtin_ctzll(bits);
            bits &= bits - 1;
            acc |= mat[(size_t)(w * 64 + b) * WPR + lane];
        }
    }
    out[(size_t)i * WPR + lane] = acc;
}

// ---- hop pass A: h = softmax_masked(rank1 e) @ W1h; 16 rows/block, K-split waves ----
__global__ __launch_bounds__(256, 4) void k_hopA(const unsigned long long* __restrict__ B1,
                                                 const unsigned long long* __restrict__ B2,
                                                 const unsigned long long* __restrict__ B3,
                                                 const float* __restrict__ s1v,
                                                 const float* __restrict__ s2v,
                                                 const float* __restrict__ s2mx,
                                                 const unsigned short* __restrict__ W1hTb,
                                                 unsigned short* __restrict__ h_rm,
                                                 unsigned short* __restrict__ h_cm,
                                                 float* __restrict__ hnorm) {
    __shared__ __align__(16) char smem[32768];   // phase1: s2l f32[4096]; phase2: LDSO[4][16][128]
    float* s2l = (float*)smem;
    float* LDSO = (float*)smem;
    __shared__ float Zp[4][16];
    __shared__ unsigned short outl[16 * HH] __attribute__((aligned(16)));
    int hop, strip;
    map_block(blockIdx.x, hop, strip);
    const int i0 = strip * 16;
    const unsigned long long* Bk = (hop == 0) ? B1 : ((hop == 1) ? B2 : B3);
    unsigned short* hrm = h_rm + (size_t)hop * NN * HH;
    unsigned short* hcm = h_cm + (size_t)hop * NN * HH;
    const int t = threadIdx.x, w = t >> 6, lane = t & 63;
    const int kg = lane >> 4, ar = lane & 15;
    // stage s2 (16 floats/thread)
#pragma unroll
    for (int j = 0; j < 4; ++j)
        *reinterpret_cast<float4*>(&s2l[t * 16 + j * 4]) =
            *reinterpret_cast<const float4*>(&s2v[t * 16 + j * 4]);
    const float s1r = s1v[i0 + ar];
    const float M = lrelu(s1r + s2mx[0]);
    __syncthreads();
    f32x4 o[8];
#pragma unroll
    for (int dt = 0; dt < 8; ++dt) o[dt] = f32x4{0.f, 0.f, 0.f, 0.f};
    float zacc = 0.f;
    // prologue bitset
    unsigned long long bw = Bk[(size_t)(i0 + ar) * WPR + w];
    // main loop: wave w owns windows w, w+4, ... ; NO barriers, NO cross-wave deps
    for (int ct = w; ct < 64; ct += 4) {
        const int c0 = ct * 64;
        const unsigned long long cbw = bw;
        // prefetch next bitset (clamped; value unused on last iter)
        bw = Bk[(size_t)(i0 + ar) * WPR + (ct + 4 < 64 ? ct + 4 : 63)];
        // batch-issue all 16 B-frags for this window
        bf16x8 breg[16];
#pragma unroll
        for (int dt = 0; dt < 8; ++dt) {
            const int d = dt * 16 + ar;
            breg[2 * dt] = *reinterpret_cast<const bf16x8*>(&W1hTb[(size_t)d * NN + c0 + kg * 8]);
            breg[2 * dt + 1] =
                *reinterpret_cast<const bf16x8*>(&W1hTb[(size_t)d * NN + c0 + 32 + kg * 8]);
        }
        // A-fragments computed pointwise (covers B-load latency)
        bf16x8 a0, a1;
#pragma unroll
        for (int cc = 0; cc < 2; ++cc) {
            const int kb = cc * 32 + kg * 8;
            const float4 va = *reinterpret_cast<const float4*>(&s2l[c0 + kb]);
            const float4 vb = *reinterpret_cast<const float4*>(&s2l[c0 + kb + 4]);
            const float sv[8] = {va.x, va.y, va.z, va.w, vb.x, vb.y, vb.z, vb.w};
            const unsigned int mb = (unsigned int)(cbw >> kb) & 0xFFu;
            bf16x8 pk;
#pragma unroll
            for (int e = 0; e < 8; ++e) {
                float f = ((mb >> e) & 1u) ? __expf(lrelu(s1r + sv[e]) - M) : 0.f;
                zacc += f;
                pk[e] = (short)f2bf(f);
            }
            if (cc == 0) a0 = pk; else a1 = pk;
        }
#pragma unroll
        for (int dt = 0; dt < 8; ++dt) {
            o[dt] = __builtin_amdgcn_mfma_f32_16x16x32_bf16(a0, breg[2 * dt], o[dt], 0, 0, 0);
            o[dt] = __builtin_amdgcn_mfma_f32_16x16x32_bf16(a1, breg[2 * dt + 1], o[dt], 0, 0, 0);
        }
    }
    // Z: reduce over kg lanes (rows = ar)
    zacc += __shfl_xor(zacc, 16, 64);
    zacc += __shfl_xor(zacc, 32, 64);
    __syncthreads();  // all waves done reading s2l; smem becomes LDSO
    if (lane < 16) Zp[w][lane] = zacc;
#pragma unroll
    for (int dt = 0; dt < 8; ++dt)
#pragma unroll
        for (int ri = 0; ri < 4; ++ri)
            LDSO[((w * 16) + (4 * kg + ri)) * 128 + dt * 16 + ar] = o[dt][ri];
    __syncthreads();
    // combine 4 waves, normalize, emit h_rm / outl / hnorm
    {
        const int row = t >> 4, l16 = t & 15;
        const float z = Zp[0][row] + Zp[1][row] + Zp[2][row] + Zp[3][row];
        const float iz = 1.f / z;
        float nsum = 0.f;
        bf16x8 pk;
#pragma unroll
        for (int j = 0; j < 8; ++j) {
            const int dd = l16 * 8 + j;
            float f = (LDSO[(0 * 16 + row) * 128 + dd] + LDSO[(1 * 16 + row) * 128 + dd] +
                       LDSO[(2 * 16 + row) * 128 + dd] + LDSO[(3 * 16 + row) * 128 + dd]) * iz;
            nsum += f * f;
            pk[j] = (short)f2bf(f);
        }
        nsum += __shfl_xor(nsum, 1, 64);
        nsum += __shfl_xor(nsum, 2, 64);
        nsum += __shfl_xor(nsum, 4, 64);
        nsum += __shfl_xor(nsum, 8, 64);
        if (l16 == 0) hnorm[(size_t)hop * NN + i0 + row] = sqrtf(nsum);
        *reinterpret_cast<bf16x8*>(&hrm[(size_t)(i0 + row) * HH + l16 * 8]) = pk;
        *reinterpret_cast<bf16x8*>(&outl[row * HH + l16 * 8]) = pk;
    }
    __syncthreads();
    {   // h_cm transpose: thread t -> dim t>>1, rows 8*(t&1)..
        const int d = t >> 1, r0 = (t & 1) * 8;
        bf16x8 v;
#pragma unroll
        for (int j = 0; j < 8; ++j) v[j] = (short)outl[(r0 + j) * HH + d];
        *reinterpret_cast<bf16x8*>(&hcm[(size_t)d * NN + i0 + r0]) = v;
    }
}

// ---- hop pass B: S=h@W2h^T, fixed-shift masked softmax, O=P@h; K-split waves ----
__global__ __launch_bounds__(256, 4) void k_hopB(const unsigned long long* __restrict__ B1,
                                                 const unsigned long long* __restrict__ B2,
                                                 const unsigned long long* __restrict__ B3,
                                                 const unsigned short* __restrict__ h_rm,
                                                 const unsigned short* __restrict__ W2hb,
                                                 const unsigned short* __restrict__ h_cm,
                                                 const float* __restrict__ hnorm,
                                                 const float* __restrict__ Mw,
                                                 unsigned short* __restrict__ accb) {
    __shared__ __align__(16) char smem[32768];   // main: Pb u16[4][1024]; final: LDSO[4][16][128]
    unsigned short* Pb = (unsigned short*)smem;
    float* LDSO = (float*)smem;
    __shared__ float Zp[4][16];
    int hop, strip;
    map_block(blockIdx.x, hop, strip);
    const int i0 = strip * 16;
    const unsigned long long* Bk = (hop == 0) ? B1 : ((hop == 1) ? B2 : B3);
    const unsigned short* hrm = h_rm + (size_t)hop * NN * HH;
    const unsigned short* hcm = h_cm + (size_t)hop * NN * HH;
    unsigned short* ab = accb + (size_t)hop * NN * HH;
    const int t = threadIdx.x, w = t >> 6, lane = t & 63;
    const int kg = lane >> 4, ar = lane & 15;
    // A-frags for S: rows i0+ar, K=128
    bf16x8 af[4];
#pragma unroll
    for (int ks = 0; ks < 4; ++ks)
        af[ks] = *reinterpret_cast<const bf16x8*>(
            &hrm[(size_t)(i0 + ar) * HH + ks * 32 + kg * 8]);
    // fixed per-row shifts for rows 4kg+ri (S D-layout rows)
    const float MwS = Mw[0];
    float hm4[4];
#pragma unroll
    for (int ri = 0; ri < 4; ++ri)
        hm4[ri] = hnorm[(size_t)hop * NN + i0 + 4 * kg + ri] * MwS;
    f32x4 o[8];
#pragma unroll
    for (int dt = 0; dt < 8; ++dt) o[dt] = f32x4{0.f, 0.f, 0.f, 0.f};
    f32x4 z4 = {0.f, 0.f, 0.f, 0.f};
    unsigned short* Pw = Pb + w * 1024;  // this wave's private granule buffer (2KB)
    // main loop: wave w owns windows w, w+4, ...; in-wave LDS only, NO barriers
    for (int ct = w; ct < 64; ct += 4) {
        const int c0 = ct * 64;
        unsigned long long bwv[4];
#pragma unroll
        for (int ri = 0; ri < 4; ++ri)
            bwv[ri] = Bk[(size_t)(i0 + 4 * kg + ri) * WPR + ct];
        // hoist PV cc=0 B-frags (consumed after S+exp -> full-phase latency cover)
        bf16x8 hv0[8];
#pragma unroll
        for (int dt = 0; dt < 8; ++dt)
            hv0[dt] = *reinterpret_cast<const bf16x8*>(
                &hcm[(size_t)(dt * 16 + ar) * NN + c0 + kg * 8]);
        // S phase
#pragma unroll
        for (int m = 0; m < 4; ++m) {
            const int cw = m * 16 + ar;        // col within window
            const size_t cb = (size_t)(c0 + cw) * HH;
            f32x4 s = {0.f, 0.f, 0.f, 0.f};
#pragma unroll
            for (int ks = 0; ks < 4; ++ks) {
                bf16x8 b = *reinterpret_cast<const bf16x8*>(&W2hb[cb + ks * 32 + kg * 8]);
                s = __builtin_amdgcn_mfma_f32_16x16x32_bf16(af[ks], b, s, 0, 0, 0);
            }
            const int gbase = ((cw >> 5) << 9) + ((((cw & 31) >> 3) << 4) << 3) + (cw & 7);
#pragma unroll
            for (int ri = 0; ri < 4; ++ri) {
                float ev = ((bwv[ri] >> cw) & 1ull) ? __expf(s[ri] - hm4[ri]) : 0.f;
                z4[ri] += ev;
                Pw[gbase + ((4 * kg + ri) << 3)] = f2bf(ev);
            }
        }
        // hoist PV cc=1 B-frags (covered by PV cc=0 MFMAs)
        bf16x8 hv1[8];
#pragma unroll
        for (int dt = 0; dt < 8; ++dt)
            hv1[dt] = *reinterpret_cast<const bf16x8*>(
                &hcm[(size_t)(dt * 16 + ar) * NN + c0 + 32 + kg * 8]);
        // PV: A from own granules (in-wave write->read, lgkmcnt-ordered)
        {
            bf16x8 a0 = *reinterpret_cast<const bf16x8*>(&Pw[lane << 3]);
#pragma unroll
            for (int dt = 0; dt < 8; ++dt)
                o[dt] = __builtin_amdgcn_mfma_f32_16x16x32_bf16(a0, hv0[dt], o[dt], 0, 0, 0);
            bf16x8 a1 = *reinterpret_cast<const bf16x8*>(&Pw[(1 << 9) + (lane << 3)]);
#pragma unroll
            for (int dt = 0; dt < 8; ++dt)
                o[dt] = __builtin_amdgcn_mfma_f32_16x16x32_bf16(a1, hv1[dt], o[dt], 0, 0, 0);
        }
    }
    // Z reduce over ar lanes (rows = 4kg+ri)
#pragma unroll
    for (int ri = 0; ri < 4; ++ri) {
        z4[ri] += __shfl_xor(z4[ri], 1, 64);
        z4[ri] += __shfl_xor(z4[ri], 2, 64);
        z4[ri] += __shfl_xor(z4[ri], 4, 64);
        z4[ri] += __shfl_xor(z4[ri], 8, 64);
    }
    __syncthreads();  // all waves done with Pb; smem becomes LDSO
    if (ar == 0) {
#pragma unroll
        for (int ri = 0; ri < 4; ++ri) Zp[w][4 * kg + ri] = z4[ri];
    }
#pragma unroll
    for (int dt = 0; dt < 8; ++dt)
#pragma unroll
        for (int ri = 0; ri < 4; ++ri)
            LDSO[((w * 16) + (4 * kg + ri)) * 128 + dt * 16 + ar] = o[dt][ri];
    __syncthreads();
    // combine + normalize + write
    {
        const int row = t >> 4, l16 = t & 15;
        const float z = Zp[0][row] + Zp[1][row] + Zp[2][row] + Zp[3][row];
        const float iz = 1.f / z;
        bf16x8 pk;
#pragma unroll
        for (int j = 0; j < 8; ++j) {
            const int dd = l16 * 8 + j;
            float f = (LDSO[(0 * 16 + row) * 128 + dd] + LDSO[(1 * 16 + row) * 128 + dd] +
                       LDSO[(2 * 16 + row) * 128 + dd] + LDSO[(3 * 16 + row) * 128 + dd]) * iz;
            pk[j] = (short)f2bf(f);
        }
        *reinterpret_cast<bf16x8*>(&ab[(size_t)(i0 + row) * HH + l16 * 8]) = pk;
    }
}

// ---- finalize: out = [U_l + sum(acc_k) ; sum(acc_k)] ----
__global__ void k_fin(const float* __restrict__ Ul, const unsigned short* __restrict__ accb,
                      float* __restrict__ out) {
    int idx = blockIdx.x * 256 + threadIdx.x;
    float a = bf2f(accb[idx]) + bf2f(accb[NN * HH + idx]) + bf2f(accb[2 * NN * HH + idx]);
    out[idx] = Ul[idx] + a;
    out[NN * HH + idx] = a;
}

extern "C" void kernel_launch(void* const* d_in, const int* in_sizes, int n_in,
                              void* d_out, int out_size, void* d_ws, size_t ws_size,
                              hipStream_t stream) {
    const float* X   = (const float*)d_in[0];
    const float* A   = (const float*)d_in[1];
    const float* Ul  = (const float*)d_in[2];
    const float* W1w = (const float*)d_in[3];
    const float* W2w = (const float*)d_in[4];
    const float* r   = (const float*)d_in[5];
    float* out = (float*)d_out;

    char* ws = (char*)d_ws;
    // Region plan (17 MB total):
    //  0..48K: hnorm (after k_s; overlays dead W1h head) | 48K: Mw
    //  64K..3.07M: accb bf16 x3 (hopB phase; overlays dead W1h tail, s-slab, W1hTb head)
    //  0..2M: W1h f32 (k_xw/k_s only)
    //  2M: s1 | 2M+64K: s2 | 2M+128K: s2mx | 2M+192K: wnorm   (dead before hopB)
    //  3M: W1hTb 1M | 4M: W2hb 1M | 5M: h_rm 3M | 8M: h_cm 3M | 11/13/15M: B1/B2/B3
    float* W1h            = (float*)(ws);
    float* hnorm          = (float*)(ws);
    float* Mw             = (float*)(ws + (48 << 10));
    unsigned short* accb  = (unsigned short*)(ws + (64 << 10));
    float* s1             = (float*)(ws + (2ull << 20));
    float* s2             = (float*)(ws + (2ull << 20) + (64 << 10));
    float* s2mx           = (float*)(ws + (2ull << 20) + (128 << 10));
    float* wnorm          = (float*)(ws + (2ull << 20) + (192 << 10));
    unsigned short* W1hTb = (unsigned short*)(ws + (3ull << 20));
    unsigned short* W2hb  = (unsigned short*)(ws + (4ull << 20));
    unsigned short* h_rm  = (unsigned short*)(ws + (5ull << 20));
    unsigned short* h_cm  = (unsigned short*)(ws + (8ull << 20));
    unsigned long long* B1 = (unsigned long long*)(ws + (11ull << 20));
    unsigned long long* B2 = (unsigned long long*)(ws + (13ull << 20));
    unsigned long long* B3 = (unsigned long long*)(ws + (15ull << 20));

    k_xw<<<NN / 16, 256, 0, stream>>>(X, W1w, W2w, W1h, W1hTb, W2hb);
    k_s<<<NN / 256, 256, 0, stream>>>(W1h, r, s1, s2);
    k_gmax<<<1, 256, 0, stream>>>(s2, s2mx);
    k_wn<<<NN / 16, 256, 0, stream>>>(W2hb, wnorm);
    k_gmax<<<1, 256, 0, stream>>>(wnorm, Mw);
    k_b1<<<NN / 4, 256, 0, stream>>>(A, B1);
    k_boolmm<<<NN / 4, 256, 0, stream>>>(B1, B1, B2);
    k_boolmm<<<NN / 4, 256, 0, stream>>>(B1, B2, B3);

    k_hopA<<<3 * (NN / 16), 256, 0, stream>>>(B1, B2, B3, s1, s2, s2mx, W1hTb,
                                              h_rm, h_cm, hnorm);
    k_hopB<<<3 * (NN / 16), 256, 0, stream>>>(B1, B2, B3, h_rm, W2hb, h_cm,
                                              hnorm, Mw, accb);
    k_fin<<<NN * HH / 256, 256, 0, stream>>>(Ul, accb, out);
}

// Round 10
// 366.678 us; speedup vs baseline: 1.0730x; 1.0730x over previous
//
#include <hip/hip_runtime.h>
#include <hip/hip_bf16.h>

// LSDAN: 3-hop masked graph attention, N=4096, IN_F=256, H=128.
//  - masks of A^k via boolean bitset reachability (A is 0/1 with self-loops).
//  - e is rank-1: e[i][j]=lrelu(s1[i]+s2[j]); hopA shift M=lrelu(s1+gmax(s2)) (valid UB).
//  - hopB: fixed per-row shift M_i=||h_i||*max_j||W2h_j|| >= rowmax (Cauchy-Schwarz).
//  - Independent-wave K-split: 16 rows/block, 4 waves own windows w,w+4,..;
//    zero barriers / zero cross-wave coupling in main loops; 4-way LDS combine.
//  - XCD<->hop affinity map keeps per-XCD B-operand streams L2-resident (R9: -18% FETCH).
//  - THIS ROUND (single variable): __launch_bounds__(256,3) -> ~170 unified VGPR/wave
//    (was (256,4)=128, compiler chopped load batches -> 1 load in flight at a time).
//    12 waves/CU * 256 CU = 768 blocks co-resident exactly. PV operand loads issued
//    at iteration top so ~36 loads stay in flight under the S-MFMA+exp phase.

#define NN 4096
#define INF 256
#define HH 128
#define WPR 64
#define ALPHA_S 0.2f

typedef short bf16x8 __attribute__((ext_vector_type(8)));
typedef float f32x4 __attribute__((ext_vector_type(4)));

__device__ __forceinline__ float lrelu(float x) { return x > 0.f ? x : ALPHA_S * x; }
__device__ __forceinline__ unsigned short f2bf(float x) {
    __hip_bfloat16 h = __float2bfloat16(x);
    return *reinterpret_cast<unsigned short*>(&h);
}
__device__ __forceinline__ float bf2f(unsigned short u) {
    return __uint_as_float(((unsigned int)u) << 16);
}

// XCD-affine (hop,strip) map: 768 blocks, residue r=x&7 ~ XCD, k=x>>3 in [0,96).
__device__ __forceinline__ void map_block(int x, int& hop, int& strip) {
    const int r = x & 7, k = x >> 3;
    if (r == 0) { hop = 0; strip = k; }
    else if (r == 1) { hop = 0; strip = 96 + k; }
    else if (r == 2) { if (k < 64) { hop = 0; strip = 192 + k; } else { hop = 1; strip = k - 64; } }
    else if (r == 3) { hop = 1; strip = 32 + k; }
    else if (r == 4) { hop = 1; strip = 128 + k; }
    else if (r == 5) { if (k < 32) { hop = 1; strip = 224 + k; } else { hop = 2; strip = k - 32; } }
    else if (r == 6) { hop = 2; strip = 64 + k; }
    else { hop = 2; strip = 160 + k; }
}

// ---- W1h = X@W1^T (f32 + bf16-transposed), W2h = X@W2^T (bf16 row-major) ----
__global__ __launch_bounds__(256) void k_xw(const float* __restrict__ X,
                                            const float* __restrict__ W1,
                                            const float* __restrict__ W2,
                                            float* __restrict__ W1h,
                                            unsigned short* __restrict__ W1hTb,
                                            unsigned short* __restrict__ W2hb) {
    __shared__ float xs[16 * INF];
    const int row0 = blockIdx.x * 16;
    const int t = threadIdx.x;
    for (int v = t; v < 16 * INF; v += 256) xs[v] = X[(size_t)row0 * INF + v];
    __syncthreads();
    const int c = t;
    const float* W = (c < HH) ? (W1 + (size_t)c * INF) : (W2 + (size_t)(c - HH) * INF);
    float acc[16];
#pragma unroll
    for (int r = 0; r < 16; ++r) acc[r] = 0.f;
    for (int k = 0; k < INF; ++k) {
        float wv = W[k];
#pragma unroll
        for (int r = 0; r < 16; ++r) acc[r] += xs[r * INF + k] * wv;
    }
    if (c < HH) {
        for (int r = 0; r < 16; ++r) {
            W1h[(size_t)(row0 + r) * HH + c] = acc[r];
            W1hTb[(size_t)c * NN + row0 + r] = f2bf(acc[r]);
        }
    } else {
        const int cc = c - HH;
        for (int r = 0; r < 16; ++r) W2hb[(size_t)(row0 + r) * HH + cc] = f2bf(acc[r]);
    }
}

// ---- s1 = W1h @ r[:H], s2 = W1h @ r[H:] ----
__global__ void k_s(const float* __restrict__ W1h, const float* __restrict__ r,
                    float* __restrict__ s1, float* __restrict__ s2) {
    int i = blockIdx.x * blockDim.x + threadIdx.x;
    if (i >= NN) return;
    float a = 0.f, b = 0.f;
    for (int h = 0; h < HH; ++h) {
        float v = W1h[(size_t)i * HH + h];
        a += v * r[h];
        b += v * r[HH + h];
    }
    s1[i] = a;
    s2[i] = b;
}

// ---- global max of 4096 floats ----
__global__ void k_gmax(const float* __restrict__ in, float* __restrict__ out) {
    __shared__ float red[256];
    const int t = threadIdx.x;
    float m = -3e38f;
    for (int i = t; i < NN; i += 256) m = fmaxf(m, in[i]);
    red[t] = m;
    __syncthreads();
    for (int off = 128; off; off >>= 1) {
        if (t < off) red[t] = fmaxf(red[t], red[t + off]);
        __syncthreads();
    }
    if (t == 0) out[0] = red[0];
}

// ---- W2h row norms ----
__global__ void k_wn(const unsigned short* __restrict__ W2hb, float* __restrict__ wnorm) {
    const int t = threadIdx.x;
    const int row = blockIdx.x * 16 + (t >> 4);
    const int sub = t & 15;
    bf16x8 v = *reinterpret_cast<const bf16x8*>(&W2hb[(size_t)row * HH + sub * 8]);
    float s = 0.f;
#pragma unroll
    for (int j = 0; j < 8; ++j) { float f = bf2f((unsigned short)v[j]); s += f * f; }
    s += __shfl_xor(s, 1, 64); s += __shfl_xor(s, 2, 64);
    s += __shfl_xor(s, 4, 64); s += __shfl_xor(s, 8, 64);
    if (sub == 0) wnorm[row] = sqrtf(s);
}

// ---- B1[i] bitset from A row i ----
__global__ void k_b1(const float* __restrict__ A, unsigned long long* __restrict__ B1) {
    const int wave = threadIdx.x >> 6;
    const int lane = threadIdx.x & 63;
    const int i = blockIdx.x * 4 + wave;
    for (int w = 0; w < WPR; ++w) {
        float a = A[(size_t)i * NN + w * 64 + lane];
        unsigned long long m = __ballot(a != 0.0f);
        if (lane == 0) B1[(size_t)i * WPR + w] = m;
    }
}

// ---- boolean matmul for reachability ----
__global__ void k_boolmm(const unsigned long long* __restrict__ srcbits,
                         const unsigned long long* __restrict__ mat,
                         unsigned long long* __restrict__ out) {
    const int wave = threadIdx.x >> 6;
    const int lane = threadIdx.x & 63;
    const int i = blockIdx.x * 4 + wave;
    unsigned long long myword = srcbits[(size_t)i * WPR + lane];
    unsigned long long acc = 0ull;
    for (int w = 0; w < WPR; ++w) {
        unsigned long long bits = __shfl(myword, w, 64);
        while (bits) {
            int b = __builtin_ctzll(bits);
            bits &= bits - 1;
            acc |= mat[(size_t)(w * 64 + b) * WPR + lane];
        }
    }
    out[(size_t)i * WPR + lane] = acc;
}

// ---- hop pass A: h = softmax_masked(rank1 e) @ W1h; 16 rows/block, K-split waves ----
__global__ __launch_bounds__(256, 3) void k_hopA(const unsigned long long* __restrict__ B1,
                                                 const unsigned long long* __restrict__ B2,
                                                 const unsigned long long* __restrict__ B3,
                                                 const float* __restrict__ s1v,
                                                 const float* __restrict__ s2v,
                                                 const float* __restrict__ s2mx,
                                                 const unsigned short* __restrict__ W1hTb,
                                                 unsigned short* __restrict__ h_rm,
                                                 unsigned short* __restrict__ h_cm,
                                                 float* __restrict__ hnorm) {
    __shared__ __align__(16) char smem[32768];   // phase1: s2l f32[4096]; phase2: LDSO[4][16][128]
    float* s2l = (float*)smem;
    float* LDSO = (float*)smem;
    __shared__ float Zp[4][16];
    __shared__ unsigned short outl[16 * HH] __attribute__((aligned(16)));
    int hop, strip;
    map_block(blockIdx.x, hop, strip);
    const int i0 = strip * 16;
    const unsigned long long* Bk = (hop == 0) ? B1 : ((hop == 1) ? B2 : B3);
    unsigned short* hrm = h_rm + (size_t)hop * NN * HH;
    unsigned short* hcm = h_cm + (size_t)hop * NN * HH;
    const int t = threadIdx.x, w = t >> 6, lane = t & 63;
    const int kg = lane >> 4, ar = lane & 15;
    // stage s2 (16 floats/thread)
#pragma unroll
    for (int j = 0; j < 4; ++j)
        *reinterpret_cast<float4*>(&s2l[t * 16 + j * 4]) =
            *reinterpret_cast<const float4*>(&s2v[t * 16 + j * 4]);
    const float s1r = s1v[i0 + ar];
    const float M = lrelu(s1r + s2mx[0]);
    __syncthreads();
    f32x4 o[8];
#pragma unroll
    for (int dt = 0; dt < 8; ++dt) o[dt] = f32x4{0.f, 0.f, 0.f, 0.f};
    float zacc = 0.f;
    unsigned long long bw = Bk[(size_t)(i0 + ar) * WPR + w];
    // main loop: wave w owns windows w, w+4, ... ; NO barriers, NO cross-wave deps
    for (int ct = w; ct < 64; ct += 4) {
        const int c0 = ct * 64;
        const unsigned long long cbw = bw;
        bw = Bk[(size_t)(i0 + ar) * WPR + (ct + 4 < 64 ? ct + 4 : 63)];
        // batch-issue all 16 B-frags for this window (now fits in regs)
        bf16x8 breg[16];
#pragma unroll
        for (int dt = 0; dt < 8; ++dt) {
            const int d = dt * 16 + ar;
            breg[2 * dt] = *reinterpret_cast<const bf16x8*>(&W1hTb[(size_t)d * NN + c0 + kg * 8]);
            breg[2 * dt + 1] =
                *reinterpret_cast<const bf16x8*>(&W1hTb[(size_t)d * NN + c0 + 32 + kg * 8]);
        }
        // A-fragments computed pointwise (covers B-load latency)
        bf16x8 a0, a1;
#pragma unroll
        for (int cc = 0; cc < 2; ++cc) {
            const int kb = cc * 32 + kg * 8;
            const float4 va = *reinterpret_cast<const float4*>(&s2l[c0 + kb]);
            const float4 vb = *reinterpret_cast<const float4*>(&s2l[c0 + kb + 4]);
            const float sv[8] = {va.x, va.y, va.z, va.w, vb.x, vb.y, vb.z, vb.w};
            const unsigned int mb = (unsigned int)(cbw >> kb) & 0xFFu;
            bf16x8 pk;
#pragma unroll
            for (int e = 0; e < 8; ++e) {
                float f = ((mb >> e) & 1u) ? __expf(lrelu(s1r + sv[e]) - M) : 0.f;
                zacc += f;
                pk[e] = (short)f2bf(f);
            }
            if (cc == 0) a0 = pk; else a1 = pk;
        }
#pragma unroll
        for (int dt = 0; dt < 8; ++dt) {
            o[dt] = __builtin_amdgcn_mfma_f32_16x16x32_bf16(a0, breg[2 * dt], o[dt], 0, 0, 0);
            o[dt] = __builtin_amdgcn_mfma_f32_16x16x32_bf16(a1, breg[2 * dt + 1], o[dt], 0, 0, 0);
        }
    }
    // Z: reduce over kg lanes (rows = ar)
    zacc += __shfl_xor(zacc, 16, 64);
    zacc += __shfl_xor(zacc, 32, 64);
    __syncthreads();  // all waves done reading s2l; smem becomes LDSO
    if (lane < 16) Zp[w][lane] = zacc;
#pragma unroll
    for (int dt = 0; dt < 8; ++dt)
#pragma unroll
        for (int ri = 0; ri < 4; ++ri)
            LDSO[((w * 16) + (4 * kg + ri)) * 128 + dt * 16 + ar] = o[dt][ri];
    __syncthreads();
    // combine 4 waves, normalize, emit h_rm / outl / hnorm
    {
        const int row = t >> 4, l16 = t & 15;
        const float z = Zp[0][row] + Zp[1][row] + Zp[2][row] + Zp[3][row];
        const float iz = 1.f / z;
        float nsum = 0.f;
        bf16x8 pk;
#pragma unroll
        for (int j = 0; j < 8; ++j) {
            const int dd = l16 * 8 + j;
            float f = (LDSO[(0 * 16 + row) * 128 + dd] + LDSO[(1 * 16 + row) * 128 + dd] +
                       LDSO[(2 * 16 + row) * 128 + dd] + LDSO[(3 * 16 + row) * 128 + dd]) * iz;
            nsum += f * f;
            pk[j] = (short)f2bf(f);
        }
        nsum += __shfl_xor(nsum, 1, 64);
        nsum += __shfl_xor(nsum, 2, 64);
        nsum += __shfl_xor(nsum, 4, 64);
        nsum += __shfl_xor(nsum, 8, 64);
        if (l16 == 0) hnorm[(size_t)hop * NN + i0 + row] = sqrtf(nsum);
        *reinterpret_cast<bf16x8*>(&hrm[(size_t)(i0 + row) * HH + l16 * 8]) = pk;
        *reinterpret_cast<bf16x8*>(&outl[row * HH + l16 * 8]) = pk;
    }
    __syncthreads();
    {   // h_cm transpose: thread t -> dim t>>1, rows 8*(t&1)..
        const int d = t >> 1, r0 = (t & 1) * 8;
        bf16x8 v;
#pragma unroll
        for (int j = 0; j < 8; ++j) v[j] = (short)outl[(r0 + j) * HH + d];
        *reinterpret_cast<bf16x8*>(&hcm[(size_t)d * NN + i0 + r0]) = v;
    }
}

// ---- hop pass B: S=h@W2h^T, fixed-shift masked softmax, O=P@h; K-split waves ----
__global__ __launch_bounds__(256, 3) void k_hopB(const unsigned long long* __restrict__ B1,
                                                 const unsigned long long* __restrict__ B2,
                                                 const unsigned long long* __restrict__ B3,
                                                 const unsigned short* __restrict__ h_rm,
                                                 const unsigned short* __restrict__ W2hb,
                                                 const unsigned short* __restrict__ h_cm,
                                                 const float* __restrict__ hnorm,
                                                 const float* __restrict__ Mw,
                                                 unsigned short* __restrict__ accb) {
    __shared__ __align__(16) char smem[32768];   // main: Pb u16[4][1024]; final: LDSO[4][16][128]
    unsigned short* Pb = (unsigned short*)smem;
    float* LDSO = (float*)smem;
    __shared__ float Zp[4][16];
    int hop, strip;
    map_block(blockIdx.x, hop, strip);
    const int i0 = strip * 16;
    const unsigned long long* Bk = (hop == 0) ? B1 : ((hop == 1) ? B2 : B3);
    const unsigned short* hrm = h_rm + (size_t)hop * NN * HH;
    const unsigned short* hcm = h_cm + (size_t)hop * NN * HH;
    unsigned short* ab = accb + (size_t)hop * NN * HH;
    const int t = threadIdx.x, w = t >> 6, lane = t & 63;
    const int kg = lane >> 4, ar = lane & 15;
    // A-frags for S: rows i0+ar, K=128
    bf16x8 af[4];
#pragma unroll
    for (int ks = 0; ks < 4; ++ks)
        af[ks] = *reinterpret_cast<const bf16x8*>(
            &hrm[(size_t)(i0 + ar) * HH + ks * 32 + kg * 8]);
    // fixed per-row shifts for rows 4kg+ri (S D-layout rows)
    const float MwS = Mw[0];
    float hm4[4];
#pragma unroll
    for (int ri = 0; ri < 4; ++ri)
        hm4[ri] = hnorm[(size_t)hop * NN + i0 + 4 * kg + ri] * MwS;
    f32x4 o[8];
#pragma unroll
    for (int dt = 0; dt < 8; ++dt) o[dt] = f32x4{0.f, 0.f, 0.f, 0.f};
    f32x4 z4 = {0.f, 0.f, 0.f, 0.f};
    unsigned short* Pw = Pb + w * 1024;  // this wave's private granule buffer (2KB)
    // main loop: wave w owns windows w, w+4, ...; in-wave LDS only, NO barriers
    for (int ct = w; ct < 64; ct += 4) {
        const int c0 = ct * 64;
        // issue ALL independent loads for this window up front (~36 in flight):
        // PV B-frags (consumed last -> full-phase latency cover)
        bf16x8 hv0[8], hv1[8];
#pragma unroll
        for (int dt = 0; dt < 8; ++dt)
            hv0[dt] = *reinterpret_cast<const bf16x8*>(
                &hcm[(size_t)(dt * 16 + ar) * NN + c0 + kg * 8]);
#pragma unroll
        for (int dt = 0; dt < 8; ++dt)
            hv1[dt] = *reinterpret_cast<const bf16x8*>(
                &hcm[(size_t)(dt * 16 + ar) * NN + c0 + 32 + kg * 8]);
        unsigned long long bwv[4];
#pragma unroll
        for (int ri = 0; ri < 4; ++ri)
            bwv[ri] = Bk[(size_t)(i0 + 4 * kg + ri) * WPR + ct];
        // S phase (W2 frags consumed as they arrive)
#pragma unroll
        for (int m = 0; m < 4; ++m) {
            const int cw = m * 16 + ar;        // col within window
            const size_t cb = (size_t)(c0 + cw) * HH;
            f32x4 s = {0.f, 0.f, 0.f, 0.f};
#pragma unroll
            for (int ks = 0; ks < 4; ++ks) {
                bf16x8 b = *reinterpret_cast<const bf16x8*>(&W2hb[cb + ks * 32 + kg * 8]);
                s = __builtin_amdgcn_mfma_f32_16x16x32_bf16(af[ks], b, s, 0, 0, 0);
            }
            const int gbase = ((cw >> 5) << 9) + ((((cw & 31) >> 3) << 4) << 3) + (cw & 7);
#pragma unroll
            for (int ri = 0; ri < 4; ++ri) {
                float ev = ((bwv[ri] >> cw) & 1ull) ? __expf(s[ri] - hm4[ri]) : 0.f;
                z4[ri] += ev;
                Pw[gbase + ((4 * kg + ri) << 3)] = f2bf(ev);
            }
        }
        // PV: A from own granules (in-wave write->read, lgkmcnt-ordered)
        {
            bf16x8 a0 = *reinterpret_cast<const bf16x8*>(&Pw[lane << 3]);
#pragma unroll
            for (int dt = 0; dt < 8; ++dt)
                o[dt] = __builtin_amdgcn_mfma_f32_16x16x32_bf16(a0, hv0[dt], o[dt], 0, 0, 0);
            bf16x8 a1 = *reinterpret_cast<const bf16x8*>(&Pw[(1 << 9) + (lane << 3)]);
#pragma unroll
            for (int dt = 0; dt < 8; ++dt)
                o[dt] = __builtin_amdgcn_mfma_f32_16x16x32_bf16(a1, hv1[dt], o[dt], 0, 0, 0);
        }
    }
    // Z reduce over ar lanes (rows = 4kg+ri)
#pragma unroll
    for (int ri = 0; ri < 4; ++ri) {
        z4[ri] += __shfl_xor(z4[ri], 1, 64);
        z4[ri] += __shfl_xor(z4[ri], 2, 64);
        z4[ri] += __shfl_xor(z4[ri], 4, 64);
        z4[ri] += __shfl_xor(z4[ri], 8, 64);
    }
    __syncthreads();  // all waves done with Pb; smem becomes LDSO
    if (ar == 0) {
#pragma unroll
        for (int ri = 0; ri < 4; ++ri) Zp[w][4 * kg + ri] = z4[ri];
    }
#pragma unroll
    for (int dt = 0; dt < 8; ++dt)
#pragma unroll
        for (int ri = 0; ri < 4; ++ri)
            LDSO[((w * 16) + (4 * kg + ri)) * 128 + dt * 16 + ar] = o[dt][ri];
    __syncthreads();
    // combine + normalize + write
    {
        const int row = t >> 4, l16 = t & 15;
        const float z = Zp[0][row] + Zp[1][row] + Zp[2][row] + Zp[3][row];
        const float iz = 1.f / z;
        bf16x8 pk;
#pragma unroll
        for (int j = 0; j < 8; ++j) {
            const int dd = l16 * 8 + j;
            float f = (LDSO[(0 * 16 + row) * 128 + dd] + LDSO[(1 * 16 + row) * 128 + dd] +
                       LDSO[(2 * 16 + row) * 128 + dd] + LDSO[(3 * 16 + row) * 128 + dd]) * iz;
            pk[j] = (short)f2bf(f);
        }
        *reinterpret_cast<bf16x8*>(&ab[(size_t)(i0 + row) * HH + l16 * 8]) = pk;
    }
}

// ---- finalize: out = [U_l + sum(acc_k) ; sum(acc_k)] ----
__global__ void k_fin(const float* __restrict__ Ul, const unsigned short* __restrict__ accb,
                      float* __restrict__ out) {
    int idx = blockIdx.x * 256 + threadIdx.x;
    float a = bf2f(accb[idx]) + bf2f(accb[NN * HH + idx]) + bf2f(accb[2 * NN * HH + idx]);
    out[idx] = Ul[idx] + a;
    out[NN * HH + idx] = a;
}

extern "C" void kernel_launch(void* const* d_in, const int* in_sizes, int n_in,
                              void* d_out, int out_size, void* d_ws, size_t ws_size,
                              hipStream_t stream) {
    const float* X   = (const float*)d_in[0];
    const float* A   = (const float*)d_in[1];
    const float* Ul  = (const float*)d_in[2];
    const float* W1w = (const float*)d_in[3];
    const float* W2w = (const float*)d_in[4];
    const float* r   = (const float*)d_in[5];
    float* out = (float*)d_out;

    char* ws = (char*)d_ws;
    // Region plan (17 MB total):
    //  0..48K: hnorm (after k_s; overlays dead W1h head) | 48K: Mw
    //  64K..3.07M: accb bf16 x3 (hopB phase; overlays dead W1h tail, s-slab, W1hTb head)
    //  0..2M: W1h f32 (k_xw/k_s only)
    //  2M: s1 | 2M+64K: s2 | 2M+128K: s2mx | 2M+192K: wnorm   (dead before hopB)
    //  3M: W1hTb 1M | 4M: W2hb 1M | 5M: h_rm 3M | 8M: h_cm 3M | 11/13/15M: B1/B2/B3
    float* W1h            = (float*)(ws);
    float* hnorm          = (float*)(ws);
    float* Mw             = (float*)(ws + (48 << 10));
    unsigned short* accb  = (unsigned short*)(ws + (64 << 10));
    float* s1             = (float*)(ws + (2ull << 20));
    float* s2             = (float*)(ws + (2ull << 20) + (64 << 10));
    float* s2mx           = (float*)(ws + (2ull << 20) + (128 << 10));
    float* wnorm          = (float*)(ws + (2ull << 20) + (192 << 10));
    unsigned short* W1hTb = (unsigned short*)(ws + (3ull << 20));
    unsigned short* W2hb  = (unsigned short*)(ws + (4ull << 20));
    unsigned short* h_rm  = (unsigned short*)(ws + (5ull << 20));
    unsigned short* h_cm  = (unsigned short*)(ws + (8ull << 20));
    unsigned long long* B1 = (unsigned long long*)(ws + (11ull << 20));
    unsigned long long* B2 = (unsigned long long*)(ws + (13ull << 20));
    unsigned long long* B3 = (unsigned long long*)(ws + (15ull << 20));

    k_xw<<<NN / 16, 256, 0, stream>>>(X, W1w, W2w, W1h, W1hTb, W2hb);
    k_s<<<NN / 256, 256, 0, stream>>>(W1h, r, s1, s2);
    k_gmax<<<1, 256, 0, stream>>>(s2, s2mx);
    k_wn<<<NN / 16, 256, 0, stream>>>(W2hb, wnorm);
    k_gmax<<<1, 256, 0, stream>>>(wnorm, Mw);
    k_b1<<<NN / 4, 256, 0, stream>>>(A, B1);
    k_boolmm<<<NN / 4, 256, 0, stream>>>(B1, B1, B2);
    k_boolmm<<<NN / 4, 256, 0, stream>>>(B1, B2, B3);

    k_hopA<<<3 * (NN / 16), 256, 0, stream>>>(B1, B2, B3, s1, s2, s2mx, W1hTb,
                                              h_rm, h_cm, hnorm);
    k_hopB<<<3 * (NN / 16), 256, 0, stream>>>(B1, B2, B3, h_rm, W2hb, h_cm,
                                              hnorm, Mw, accb);
    k_fin<<<NN * HH / 256, 256, 0, stream>>>(Ul, accb, out);
}

// Round 11
// 305.698 us; speedup vs baseline: 1.2870x; 1.1995x over previous
//
#include <hip/hip_runtime.h>
#include <hip/hip_bf16.h>

// LSDAN: 3-hop masked graph attention, N=4096, IN_F=256, H=128.
//  - masks of A^k via boolean bitset reachability (A is 0/1 with self-loops).
//  - e is rank-1: e[i][j]=lrelu(s1[i]+s2[j]); hopA shift M=lrelu(s1+gmax(s2)) (valid UB).
//  - hopB: fixed per-row shift M_i=||h_i||*max_j||W2h_j|| >= rowmax (Cauchy-Schwarz).
//  - THIS ROUND: T3-lite staged pipeline. B-operands staged via global_load_lds(16B)
//    into double-buffered LDS tiles (pre-swizzled SOURCE + swizzled read = conflict-free,
//    rule #21). Mid-iteration barrier is raw s_waitcnt lgkmcnt(0)+s_barrier so staging
//    vmcnt stays outstanding across it; end-of-iter __syncthreads drains loads issued
//    a full iteration earlier. 32 rows/block, 8 waves, 64-col windows, 2 blocks/CU.

#define NN 4096
#define INF 256
#define HH 128
#define WPR 64
#define ALPHA_S 0.2f
#define NT 64

typedef short bf16x8 __attribute__((ext_vector_type(8)));
typedef float f32x4 __attribute__((ext_vector_type(4)));

#define MFMA(a, b, c) __builtin_amdgcn_mfma_f32_16x16x32_bf16(a, b, c, 0, 0, 0)

__device__ __forceinline__ float lrelu(float x) { return x > 0.f ? x : ALPHA_S * x; }
__device__ __forceinline__ unsigned short f2bf(float x) {
    __hip_bfloat16 h = __float2bfloat16(x);
    return *reinterpret_cast<unsigned short*>(&h);
}
__device__ __forceinline__ float bf2f(unsigned short u) {
    return __uint_as_float(((unsigned int)u) << 16);
}
// async global->LDS 16B: per-lane global src, wave-uniform LDS base (+lane*16 by HW)
__device__ __forceinline__ void gld16(const void* g, void* l) {
    __builtin_amdgcn_global_load_lds(
        (const __attribute__((address_space(1))) unsigned int*)g,
        (__attribute__((address_space(3))) unsigned int*)l, 16, 0, 0);
}

// XCD-affine (hop,strip) map for 384 blocks: r=x&7 ~ XCD, k=x>>3 in [0,48).
__device__ __forceinline__ void map384(int x, int& hop, int& strip) {
    const int r = x & 7, k = x >> 3;
    if (r == 0) { hop = 0; strip = k; }
    else if (r == 1) { hop = 0; strip = 48 + k; }
    else if (r == 2) { if (k < 32) { hop = 0; strip = 96 + k; } else { hop = 1; strip = k - 32; } }
    else if (r == 3) { hop = 1; strip = 16 + k; }
    else if (r == 4) { hop = 1; strip = 64 + k; }
    else if (r == 5) { if (k < 16) { hop = 1; strip = 112 + k; } else { hop = 2; strip = k - 16; } }
    else if (r == 6) { hop = 2; strip = 32 + k; }
    else { hop = 2; strip = 80 + k; }
}

// ---- W1h = X@W1^T (f32 + bf16-transposed), W2h = X@W2^T (bf16 row-major) ----
__global__ __launch_bounds__(256) void k_xw(const float* __restrict__ X,
                                            const float* __restrict__ W1,
                                            const float* __restrict__ W2,
                                            float* __restrict__ W1h,
                                            unsigned short* __restrict__ W1hTb,
                                            unsigned short* __restrict__ W2hb) {
    __shared__ float xs[16 * INF];
    const int row0 = blockIdx.x * 16;
    const int t = threadIdx.x;
    for (int v = t; v < 16 * INF; v += 256) xs[v] = X[(size_t)row0 * INF + v];
    __syncthreads();
    const int c = t;
    const float* W = (c < HH) ? (W1 + (size_t)c * INF) : (W2 + (size_t)(c - HH) * INF);
    float acc[16];
#pragma unroll
    for (int r = 0; r < 16; ++r) acc[r] = 0.f;
    for (int k = 0; k < INF; ++k) {
        float wv = W[k];
#pragma unroll
        for (int r = 0; r < 16; ++r) acc[r] += xs[r * INF + k] * wv;
    }
    if (c < HH) {
        for (int r = 0; r < 16; ++r) {
            W1h[(size_t)(row0 + r) * HH + c] = acc[r];
            W1hTb[(size_t)c * NN + row0 + r] = f2bf(acc[r]);
        }
    } else {
        const int cc = c - HH;
        for (int r = 0; r < 16; ++r) W2hb[(size_t)(row0 + r) * HH + cc] = f2bf(acc[r]);
    }
}

// ---- s1 = W1h @ r[:H], s2 = W1h @ r[H:] ----
__global__ void k_s(const float* __restrict__ W1h, const float* __restrict__ r,
                    float* __restrict__ s1, float* __restrict__ s2) {
    int i = blockIdx.x * blockDim.x + threadIdx.x;
    if (i >= NN) return;
    float a = 0.f, b = 0.f;
    for (int h = 0; h < HH; ++h) {
        float v = W1h[(size_t)i * HH + h];
        a += v * r[h];
        b += v * r[HH + h];
    }
    s1[i] = a;
    s2[i] = b;
}

// ---- global max of 4096 floats ----
__global__ void k_gmax(const float* __restrict__ in, float* __restrict__ out) {
    __shared__ float red[256];
    const int t = threadIdx.x;
    float m = -3e38f;
    for (int i = t; i < NN; i += 256) m = fmaxf(m, in[i]);
    red[t] = m;
    __syncthreads();
    for (int off = 128; off; off >>= 1) {
        if (t < off) red[t] = fmaxf(red[t], red[t + off]);
        __syncthreads();
    }
    if (t == 0) out[0] = red[0];
}

// ---- W2h row norms ----
__global__ void k_wn(const unsigned short* __restrict__ W2hb, float* __restrict__ wnorm) {
    const int t = threadIdx.x;
    const int row = blockIdx.x * 16 + (t >> 4);
    const int sub = t & 15;
    bf16x8 v = *reinterpret_cast<const bf16x8*>(&W2hb[(size_t)row * HH + sub * 8]);
    float s = 0.f;
#pragma unroll
    for (int j = 0; j < 8; ++j) { float f = bf2f((unsigned short)v[j]); s += f * f; }
    s += __shfl_xor(s, 1, 64); s += __shfl_xor(s, 2, 64);
    s += __shfl_xor(s, 4, 64); s += __shfl_xor(s, 8, 64);
    if (sub == 0) wnorm[row] = sqrtf(s);
}

// ---- B1[i] bitset from A row i ----
__global__ void k_b1(const float* __restrict__ A, unsigned long long* __restrict__ B1) {
    const int wave = threadIdx.x >> 6;
    const int lane = threadIdx.x & 63;
    const int i = blockIdx.x * 4 + wave;
    for (int w = 0; w < WPR; ++w) {
        float a = A[(size_t)i * NN + w * 64 + lane];
        unsigned long long m = __ballot(a != 0.0f);
        if (lane == 0) B1[(size_t)i * WPR + w] = m;
    }
}

// ---- boolean matmul for reachability ----
__global__ void k_boolmm(const unsigned long long* __restrict__ srcbits,
                         const unsigned long long* __restrict__ mat,
                         unsigned long long* __restrict__ out) {
    const int wave = threadIdx.x >> 6;
    const int lane = threadIdx.x & 63;
    const int i = blockIdx.x * 4 + wave;
    unsigned long long myword = srcbits[(size_t)i * WPR + lane];
    unsigned long long acc = 0ull;
    for (int w = 0; w < WPR; ++w) {
        unsigned long long bits = __shfl(myword, w, 64);
        while (bits) {
            int b = __builtin_ctzll(bits);
            bits &= bits - 1;
            acc |= mat[(size_t)(w * 64 + b) * WPR + lane];
        }
    }
    out[(size_t)i * WPR + lane] = acc;
}

// ---- hop pass A: h = softmax_masked(rank1 e) @ W1h; staged pipeline ----
__global__ __launch_bounds__(512, 4) void k_hopA(const unsigned long long* __restrict__ B1,
                                                 const unsigned long long* __restrict__ B2,
                                                 const unsigned long long* __restrict__ B3,
                                                 const float* __restrict__ s1v,
                                                 const float* __restrict__ s2v,
                                                 const float* __restrict__ s2mx,
                                                 const unsigned short* __restrict__ W1hTb,
                                                 unsigned short* __restrict__ h_rm,
                                                 unsigned short* __restrict__ h_cm,
                                                 float* __restrict__ hnorm) {
    __shared__ __align__(16) char smem[49152];
    unsigned short (*W1buf)[8192] = (unsigned short(*)[8192])smem;  // [2][16KB] B tiles
    float* s2l = (float*)(smem + 32768);                            // 16KB
    float* outl = (float*)smem;                                     // epi alias over W1buf
    __shared__ float Zl[32];
    int hop, strip;
    map384(blockIdx.x, hop, strip);
    const int i0 = strip * 32;
    const unsigned long long* Bk = (hop == 0) ? B1 : ((hop == 1) ? B2 : B3);
    unsigned short* hrm = h_rm + (size_t)hop * NN * HH;
    unsigned short* hcm = h_cm + (size_t)hop * NN * HH;
    const int t = threadIdx.x, w = t >> 6, lane = t & 63;
    const int wr = w >> 2, wc = w & 3, kg = lane >> 4, ar = lane & 15;
    // stage s2 (8 f32/thread)
    *reinterpret_cast<float4*>(&s2l[t * 8]) = *reinterpret_cast<const float4*>(&s2v[t * 8]);
    *reinterpret_cast<float4*>(&s2l[t * 8 + 4]) = *reinterpret_cast<const float4*>(&s2v[t * 8 + 4]);
    // tile stage: [d=128][8 c-granules], slot s holds source granule s^(d&7)
    auto stage = [&](int buf, int cn) {
#pragma unroll
        for (int j = 0; j < 2; ++j) {
            const int G = w * 128 + j * 64 + lane;
            const int d = G >> 3, cs = G & 7;
            gld16(&W1hTb[(size_t)d * NN + cn + ((cs ^ (d & 7)) << 3)],
                  &W1buf[buf][(w * 128 + j * 64) * 8]);
        }
    };
    stage(0, 0);
    const float s1r = s1v[i0 + 16 * wr + ar];
    const float M = lrelu(s1r + s2mx[0]);
    f32x4 o0 = {0.f, 0.f, 0.f, 0.f}, o1 = {0.f, 0.f, 0.f, 0.f};
    float zacc = 0.f;
    __syncthreads();  // s2l + tile0 ready (vmcnt drained by compiler)
    for (int ct = 0; ct < NT; ++ct) {
        const int p = ct & 1;
        if (ct < NT - 1) stage(p ^ 1, (ct + 1) * 64);
        const unsigned long long bw = Bk[(size_t)(i0 + 16 * wr + ar) * WPR + ct];
        const int c0 = ct * 64;
        bf16x8 a[2];
#pragma unroll
        for (int kc = 0; kc < 2; ++kc) {
            const int kb = c0 + kc * 32 + kg * 8;
            const float4 va = *reinterpret_cast<const float4*>(&s2l[kb]);
            const float4 vb = *reinterpret_cast<const float4*>(&s2l[kb + 4]);
            const float sv[8] = {va.x, va.y, va.z, va.w, vb.x, vb.y, vb.z, vb.w};
            const unsigned int mb = (unsigned int)(bw >> (kc * 32 + kg * 8)) & 0xFFu;
            bf16x8 pk;
#pragma unroll
            for (int e = 0; e < 8; ++e) {
                float f = ((mb >> e) & 1u) ? __expf(lrelu(s1r + sv[e]) - M) : 0.f;
                zacc += f;
                pk[e] = (short)f2bf(f);
            }
            a[kc] = pk;
        }
#pragma unroll
        for (int kc = 0; kc < 2; ++kc) {
            const int g = kc * 4 + kg;
            const int d0 = 32 * wc + ar, d1 = d0 + 16;
            const bf16x8 b0 = *reinterpret_cast<const bf16x8*>(
                &W1buf[p][(d0 * 8 + (g ^ (d0 & 7))) * 8]);
            const bf16x8 b1 = *reinterpret_cast<const bf16x8*>(
                &W1buf[p][(d1 * 8 + (g ^ (d1 & 7))) * 8]);
            o0 = MFMA(a[kc], b0, o0);
            o1 = MFMA(a[kc], b1, o1);
        }
        __syncthreads();  // frees buf p for ct+2's stage; drains ct+1 loads
    }
    // Z (wc==0 wave covers full window set; reduce over kg)
    zacc += __shfl_xor(zacc, 16, 64);
    zacc += __shfl_xor(zacc, 32, 64);
    if (wc == 0 && lane < 16) Zl[16 * wr + lane] = zacc;
    __syncthreads();
    // normalize into outl (aliases W1buf, safe post-barrier)
#pragma unroll
    for (int ri = 0; ri < 4; ++ri) {
        const int row = 16 * wr + 4 * kg + ri;
        const float iz = 1.f / Zl[row];
        outl[row * 128 + 32 * wc + ar] = o0[ri] * iz;
        outl[row * 128 + 32 * wc + 16 + ar] = o1[ri] * iz;
    }
    __syncthreads();
    {   // h_rm + hnorm: thread t -> row t>>4, 8 dims
        const int row = t >> 4, l16 = t & 15;
        float nsum = 0.f;
        bf16x8 pk;
#pragma unroll
        for (int j = 0; j < 8; ++j) {
            float f = outl[row * 128 + l16 * 8 + j];
            nsum += f * f;
            pk[j] = (short)f2bf(f);
        }
        nsum += __shfl_xor(nsum, 1, 64);
        nsum += __shfl_xor(nsum, 2, 64);
        nsum += __shfl_xor(nsum, 4, 64);
        nsum += __shfl_xor(nsum, 8, 64);
        if (l16 == 0) hnorm[(size_t)hop * NN + i0 + row] = sqrtf(nsum);
        *reinterpret_cast<bf16x8*>(&hrm[(size_t)(i0 + row) * HH + l16 * 8]) = pk;
    }
    {   // h_cm transpose: thread t -> dim t>>2, rows (t&3)*8..
        const int d = t >> 2, r0 = (t & 3) * 8;
        bf16x8 v;
#pragma unroll
        for (int j = 0; j < 8; ++j) v[j] = (short)f2bf(outl[(r0 + j) * 128 + d]);
        *reinterpret_cast<bf16x8*>(&hcm[(size_t)d * NN + i0 + r0]) = v;
    }
}

// ---- hop pass B: S=h@W2h^T, fixed-shift masked softmax, O=P@h; staged pipeline ----
__global__ __launch_bounds__(512, 4) void k_hopB(const unsigned long long* __restrict__ B1,
                                                 const unsigned long long* __restrict__ B2,
                                                 const unsigned long long* __restrict__ B3,
                                                 const unsigned short* __restrict__ h_rm,
                                                 const unsigned short* __restrict__ W2hb,
                                                 const unsigned short* __restrict__ h_cm,
                                                 const float* __restrict__ hnorm,
                                                 const float* __restrict__ Mw,
                                                 unsigned short* __restrict__ accb) {
    __shared__ __align__(16) char smem[69632];
    unsigned short (*W2buf)[8192] = (unsigned short(*)[8192])smem;            // [2][16KB]
    unsigned short (*hTbuf)[8192] = (unsigned short(*)[8192])(smem + 32768);  // [2][16KB]
    unsigned short* Pb = (unsigned short*)(smem + 65536);                     // 4KB granules
    float* outl = (float*)smem;                                               // epi alias
    __shared__ float Zp[2][4][16];
    int hop, strip;
    map384(blockIdx.x, hop, strip);
    const int i0 = strip * 32;
    const unsigned long long* Bk = (hop == 0) ? B1 : ((hop == 1) ? B2 : B3);
    const unsigned short* hrm = h_rm + (size_t)hop * NN * HH;
    const unsigned short* hcm = h_cm + (size_t)hop * NN * HH;
    unsigned short* ab = accb + (size_t)hop * NN * HH;
    const int t = threadIdx.x, w = t >> 6, lane = t & 63;
    const int wr = w >> 2, wc = w & 3, kg = lane >> 4, ar = lane & 15;
    // A-frags for S: h rows i0+16wr+ar, K=128
    bf16x8 af[4];
#pragma unroll
    for (int ks = 0; ks < 4; ++ks)
        af[ks] = *reinterpret_cast<const bf16x8*>(
            &hrm[(size_t)(i0 + 16 * wr + ar) * HH + ks * 32 + kg * 8]);
    const float MwS = Mw[0];
    float hm4[4];
#pragma unroll
    for (int ri = 0; ri < 4; ++ri)
        hm4[ri] = hnorm[(size_t)hop * NN + i0 + 16 * wr + 4 * kg + ri] * MwS;
    // stage: W2 tile [col=64][16 k-granules], hT tile [d=128][8 c-granules]; swz sources
    auto stage = [&](int buf, int cn) {
#pragma unroll
        for (int j = 0; j < 2; ++j) {
            const int G = w * 128 + j * 64 + lane;
            const int col = G >> 4, s = G & 15;
            gld16(&W2hb[(size_t)(cn + col) * HH + ((s ^ (col & 7)) << 3)],
                  &W2buf[buf][(w * 128 + j * 64) * 8]);
            const int d = G >> 3, cs = G & 7;
            gld16(&hcm[(size_t)d * NN + cn + ((cs ^ (d & 7)) << 3)],
                  &hTbuf[buf][(w * 128 + j * 64) * 8]);
        }
    };
    stage(0, 0);
    f32x4 o0 = {0.f, 0.f, 0.f, 0.f}, o1 = {0.f, 0.f, 0.f, 0.f};
    f32x4 z4 = {0.f, 0.f, 0.f, 0.f};
    __syncthreads();
    for (int ct = 0; ct < NT; ++ct) {
        const int p = ct & 1;
        if (ct < NT - 1) stage(p ^ 1, (ct + 1) * 64);
        unsigned long long bwv[4];
#pragma unroll
        for (int ri = 0; ri < 4; ++ri)
            bwv[ri] = Bk[(size_t)(i0 + 16 * wr + 4 * kg + ri) * WPR + ct];
        // S: wave computes S[16 rows][16 cols of window]
        const int cw = 16 * wc + ar;
        f32x4 s = {0.f, 0.f, 0.f, 0.f};
#pragma unroll
        for (int ks = 0; ks < 4; ++ks) {
            const int g = ks * 4 + kg;
            const bf16x8 b = *reinterpret_cast<const bf16x8*>(
                &W2buf[p][(cw * 16 + (g ^ (cw & 7))) * 8]);
            s = MFMA(af[ks], b, s);
        }
        // masked exp -> P granules
#pragma unroll
        for (int ri = 0; ri < 4; ++ri) {
            const float ev = ((bwv[ri] >> cw) & 1ull) ? __expf(s[ri] - hm4[ri]) : 0.f;
            z4[ri] += ev;
            const int kc = cw >> 5, kgp = (cw & 31) >> 3;
            const int lp = (kgp << 4) | (4 * kg + ri);
            Pb[((wr * 2 + kc) * 64 + lp) * 8 + (cw & 7)] = f2bf(ev);
        }
        // mid barrier WITHOUT vmcnt drain: staging loads stay in flight
        asm volatile("s_waitcnt lgkmcnt(0)\n\ts_barrier" ::: "memory");
        // PV
#pragma unroll
        for (int kc = 0; kc < 2; ++kc) {
            const bf16x8 a = *reinterpret_cast<const bf16x8*>(
                &Pb[((wr * 2 + kc) * 64 + lane) * 8]);
            const int g = kc * 4 + kg;
            const int d0 = 32 * wc + ar, d1 = d0 + 16;
            const bf16x8 b0 = *reinterpret_cast<const bf16x8*>(
                &hTbuf[p][(d0 * 8 + (g ^ (d0 & 7))) * 8]);
            const bf16x8 b1 = *reinterpret_cast<const bf16x8*>(
                &hTbuf[p][(d1 * 8 + (g ^ (d1 & 7))) * 8]);
            o0 = MFMA(a, b0, o0);
            o1 = MFMA(a, b1, o1);
        }
        __syncthreads();  // frees P + buf p; drains ct+1 staging loads
    }
    // Z reduce over ar lanes, publish per-wc partials
#pragma unroll
    for (int ri = 0; ri < 4; ++ri) {
        z4[ri] += __shfl_xor(z4[ri], 1, 64);
        z4[ri] += __shfl_xor(z4[ri], 2, 64);
        z4[ri] += __shfl_xor(z4[ri], 4, 64);
        z4[ri] += __shfl_xor(z4[ri], 8, 64);
    }
    if (ar == 0) {
#pragma unroll
        for (int ri = 0; ri < 4; ++ri) Zp[wr][wc][4 * kg + ri] = z4[ri];
    }
    __syncthreads();
#pragma unroll
    for (int ri = 0; ri < 4; ++ri) {
        const int r16 = 4 * kg + ri;
        const int row = 16 * wr + r16;
        const float iz =
            1.f / (Zp[wr][0][r16] + Zp[wr][1][r16] + Zp[wr][2][r16] + Zp[wr][3][r16]);
        outl[row * 128 + 32 * wc + ar] = o0[ri] * iz;
        outl[row * 128 + 32 * wc + 16 + ar] = o1[ri] * iz;
    }
    __syncthreads();
    {   // coalesced bf16 write
        const int row = t >> 4, l16 = t & 15;
        bf16x8 pk;
#pragma unroll
        for (int j = 0; j < 8; ++j) pk[j] = (short)f2bf(outl[row * 128 + l16 * 8 + j]);
        *reinterpret_cast<bf16x8*>(&ab[(size_t)(i0 + row) * HH + l16 * 8]) = pk;
    }
}

// ---- finalize: out = [U_l + sum(acc_k) ; sum(acc_k)] ----
__global__ void k_fin(const float* __restrict__ Ul, const unsigned short* __restrict__ accb,
                      float* __restrict__ out) {
    int idx = blockIdx.x * 256 + threadIdx.x;
    float a = bf2f(accb[idx]) + bf2f(accb[NN * HH + idx]) + bf2f(accb[2 * NN * HH + idx]);
    out[idx] = Ul[idx] + a;
    out[NN * HH + idx] = a;
}

extern "C" void kernel_launch(void* const* d_in, const int* in_sizes, int n_in,
                              void* d_out, int out_size, void* d_ws, size_t ws_size,
                              hipStream_t stream) {
    const float* X   = (const float*)d_in[0];
    const float* A   = (const float*)d_in[1];
    const float* Ul  = (const float*)d_in[2];
    const float* W1w = (const float*)d_in[3];
    const float* W2w = (const float*)d_in[4];
    const float* r   = (const float*)d_in[5];
    float* out = (float*)d_out;

    char* ws = (char*)d_ws;
    // Region plan (17 MB total), unchanged from R10.
    float* W1h            = (float*)(ws);
    float* hnorm          = (float*)(ws);
    float* Mw             = (float*)(ws + (48 << 10));
    unsigned short* accb  = (unsigned short*)(ws + (64 << 10));
    float* s1             = (float*)(ws + (2ull << 20));
    float* s2             = (float*)(ws + (2ull << 20) + (64 << 10));
    float* s2mx           = (float*)(ws + (2ull << 20) + (128 << 10));
    float* wnorm          = (float*)(ws + (2ull << 20) + (192 << 10));
    unsigned short* W1hTb = (unsigned short*)(ws + (3ull << 20));
    unsigned short* W2hb  = (unsigned short*)(ws + (4ull << 20));
    unsigned short* h_rm  = (unsigned short*)(ws + (5ull << 20));
    unsigned short* h_cm  = (unsigned short*)(ws + (8ull << 20));
    unsigned long long* B1 = (unsigned long long*)(ws + (11ull << 20));
    unsigned long long* B2 = (unsigned long long*)(ws + (13ull << 20));
    unsigned long long* B3 = (unsigned long long*)(ws + (15ull << 20));

    k_xw<<<NN / 16, 256, 0, stream>>>(X, W1w, W2w, W1h, W1hTb, W2hb);
    k_s<<<NN / 256, 256, 0, stream>>>(W1h, r, s1, s2);
    k_gmax<<<1, 256, 0, stream>>>(s2, s2mx);
    k_wn<<<NN / 16, 256, 0, stream>>>(W2hb, wnorm);
    k_gmax<<<1, 256, 0, stream>>>(wnorm, Mw);
    k_b1<<<NN / 4, 256, 0, stream>>>(A, B1);
    k_boolmm<<<NN / 4, 256, 0, stream>>>(B1, B1, B2);
    k_boolmm<<<NN / 4, 256, 0, stream>>>(B1, B2, B3);

    k_hopA<<<3 * (NN / 32), 512, 0, stream>>>(B1, B2, B3, s1, s2, s2mx, W1hTb,
                                              h_rm, h_cm, hnorm);
    k_hopB<<<3 * (NN / 32), 512, 0, stream>>>(B1, B2, B3, h_rm, W2hb, h_cm,
                                              hnorm, Mw, accb);
    k_fin<<<NN * HH / 256, 256, 0, stream>>>(Ul, accb, out);
}

// Round 12
// 278.051 us; speedup vs baseline: 1.4150x; 1.0994x over previous
//
#include <hip/hip_runtime.h>
#include <hip/hip_bf16.h>

// LSDAN: 3-hop masked graph attention, N=4096, IN_F=256, H=128.
//  - masks of A^k via boolean bitset reachability (A is 0/1 with self-loops).
//  - e is rank-1: e[i][j]=lrelu(s1[i]+s2[j]); hopA shift M=lrelu(s1+gmax(s2)) (valid UB).
//  - hopB: fixed per-row shift M_i=||h_i||*max_j||W2h_j|| >= rowmax (Cauchy-Schwarz).
//  - Staged pipeline (R11): B-operands via global_load_lds(16B) into double-buffered
//    LDS tiles (pre-swizzled SOURCE + swizzled read, rule #21). Mid-iter barrier is
//    raw s_waitcnt lgkmcnt(0)+s_barrier (staging vmcnt stays in flight across it).
//  - THIS ROUND: hopA exp de-duplication. R11 hopA computed identical P fragments in
//    all 4 wc-waves (VALUBusy 46%). Now each wave computes only its 16 cols/window
//    (4 exp/lane/iter, was 16) into the shared P-granule buffer (hopB's proven
//    layout), then PV reads granules. hopA == hopB minus S-MFMA.

#define NN 4096
#define INF 256
#define HH 128
#define WPR 64
#define ALPHA_S 0.2f
#define NT 64

typedef short bf16x8 __attribute__((ext_vector_type(8)));
typedef float f32x4 __attribute__((ext_vector_type(4)));

#define MFMA(a, b, c) __builtin_amdgcn_mfma_f32_16x16x32_bf16(a, b, c, 0, 0, 0)

__device__ __forceinline__ float lrelu(float x) { return x > 0.f ? x : ALPHA_S * x; }
__device__ __forceinline__ unsigned short f2bf(float x) {
    __hip_bfloat16 h = __float2bfloat16(x);
    return *reinterpret_cast<unsigned short*>(&h);
}
__device__ __forceinline__ float bf2f(unsigned short u) {
    return __uint_as_float(((unsigned int)u) << 16);
}
// async global->LDS 16B: per-lane global src, wave-uniform LDS base (+lane*16 by HW)
__device__ __forceinline__ void gld16(const void* g, void* l) {
    __builtin_amdgcn_global_load_lds(
        (const __attribute__((address_space(1))) unsigned int*)g,
        (__attribute__((address_space(3))) unsigned int*)l, 16, 0, 0);
}

// XCD-affine (hop,strip) map for 384 blocks: r=x&7 ~ XCD, k=x>>3 in [0,48).
__device__ __forceinline__ void map384(int x, int& hop, int& strip) {
    const int r = x & 7, k = x >> 3;
    if (r == 0) { hop = 0; strip = k; }
    else if (r == 1) { hop = 0; strip = 48 + k; }
    else if (r == 2) { if (k < 32) { hop = 0; strip = 96 + k; } else { hop = 1; strip = k - 32; } }
    else if (r == 3) { hop = 1; strip = 16 + k; }
    else if (r == 4) { hop = 1; strip = 64 + k; }
    else if (r == 5) { if (k < 16) { hop = 1; strip = 112 + k; } else { hop = 2; strip = k - 16; } }
    else if (r == 6) { hop = 2; strip = 32 + k; }
    else { hop = 2; strip = 80 + k; }
}

// ---- W1h = X@W1^T (f32 + bf16-transposed), W2h = X@W2^T (bf16 row-major) ----
__global__ __launch_bounds__(256) void k_xw(const float* __restrict__ X,
                                            const float* __restrict__ W1,
                                            const float* __restrict__ W2,
                                            float* __restrict__ W1h,
                                            unsigned short* __restrict__ W1hTb,
                                            unsigned short* __restrict__ W2hb) {
    __shared__ float xs[16 * INF];
    const int row0 = blockIdx.x * 16;
    const int t = threadIdx.x;
    for (int v = t; v < 16 * INF; v += 256) xs[v] = X[(size_t)row0 * INF + v];
    __syncthreads();
    const int c = t;
    const float* W = (c < HH) ? (W1 + (size_t)c * INF) : (W2 + (size_t)(c - HH) * INF);
    float acc[16];
#pragma unroll
    for (int r = 0; r < 16; ++r) acc[r] = 0.f;
    for (int k = 0; k < INF; ++k) {
        float wv = W[k];
#pragma unroll
        for (int r = 0; r < 16; ++r) acc[r] += xs[r * INF + k] * wv;
    }
    if (c < HH) {
        for (int r = 0; r < 16; ++r) {
            W1h[(size_t)(row0 + r) * HH + c] = acc[r];
            W1hTb[(size_t)c * NN + row0 + r] = f2bf(acc[r]);
        }
    } else {
        const int cc = c - HH;
        for (int r = 0; r < 16; ++r) W2hb[(size_t)(row0 + r) * HH + cc] = f2bf(acc[r]);
    }
}

// ---- s1 = W1h @ r[:H], s2 = W1h @ r[H:] ----
__global__ void k_s(const float* __restrict__ W1h, const float* __restrict__ r,
                    float* __restrict__ s1, float* __restrict__ s2) {
    int i = blockIdx.x * blockDim.x + threadIdx.x;
    if (i >= NN) return;
    float a = 0.f, b = 0.f;
    for (int h = 0; h < HH; ++h) {
        float v = W1h[(size_t)i * HH + h];
        a += v * r[h];
        b += v * r[HH + h];
    }
    s1[i] = a;
    s2[i] = b;
}

// ---- global max of 4096 floats ----
__global__ void k_gmax(const float* __restrict__ in, float* __restrict__ out) {
    __shared__ float red[256];
    const int t = threadIdx.x;
    float m = -3e38f;
    for (int i = t; i < NN; i += 256) m = fmaxf(m, in[i]);
    red[t] = m;
    __syncthreads();
    for (int off = 128; off; off >>= 1) {
        if (t < off) red[t] = fmaxf(red[t], red[t + off]);
        __syncthreads();
    }
    if (t == 0) out[0] = red[0];
}

// ---- W2h row norms ----
__global__ void k_wn(const unsigned short* __restrict__ W2hb, float* __restrict__ wnorm) {
    const int t = threadIdx.x;
    const int row = blockIdx.x * 16 + (t >> 4);
    const int sub = t & 15;
    bf16x8 v = *reinterpret_cast<const bf16x8*>(&W2hb[(size_t)row * HH + sub * 8]);
    float s = 0.f;
#pragma unroll
    for (int j = 0; j < 8; ++j) { float f = bf2f((unsigned short)v[j]); s += f * f; }
    s += __shfl_xor(s, 1, 64); s += __shfl_xor(s, 2, 64);
    s += __shfl_xor(s, 4, 64); s += __shfl_xor(s, 8, 64);
    if (sub == 0) wnorm[row] = sqrtf(s);
}

// ---- B1[i] bitset from A row i ----
__global__ void k_b1(const float* __restrict__ A, unsigned long long* __restrict__ B1) {
    const int wave = threadIdx.x >> 6;
    const int lane = threadIdx.x & 63;
    const int i = blockIdx.x * 4 + wave;
    for (int w = 0; w < WPR; ++w) {
        float a = A[(size_t)i * NN + w * 64 + lane];
        unsigned long long m = __ballot(a != 0.0f);
        if (lane == 0) B1[(size_t)i * WPR + w] = m;
    }
}

// ---- boolean matmul for reachability ----
__global__ void k_boolmm(const unsigned long long* __restrict__ srcbits,
                         const unsigned long long* __restrict__ mat,
                         unsigned long long* __restrict__ out) {
    const int wave = threadIdx.x >> 6;
    const int lane = threadIdx.x & 63;
    const int i = blockIdx.x * 4 + wave;
    unsigned long long myword = srcbits[(size_t)i * WPR + lane];
    unsigned long long acc = 0ull;
    for (int w = 0; w < WPR; ++w) {
        unsigned long long bits = __shfl(myword, w, 64);
        while (bits) {
            int b = __builtin_ctzll(bits);
            bits &= bits - 1;
            acc |= mat[(size_t)(w * 64 + b) * WPR + lane];
        }
    }
    out[(size_t)i * WPR + lane] = acc;
}

// ---- hop pass A: h = softmax_masked(rank1 e) @ W1h; staged pipeline, shared P ----
__global__ __launch_bounds__(512, 4) void k_hopA(const unsigned long long* __restrict__ B1,
                                                 const unsigned long long* __restrict__ B2,
                                                 const unsigned long long* __restrict__ B3,
                                                 const float* __restrict__ s1v,
                                                 const float* __restrict__ s2v,
                                                 const float* __restrict__ s2mx,
                                                 const unsigned short* __restrict__ W1hTb,
                                                 unsigned short* __restrict__ h_rm,
                                                 unsigned short* __restrict__ h_cm,
                                                 float* __restrict__ hnorm) {
    __shared__ __align__(16) char smem[53248];
    unsigned short (*W1buf)[8192] = (unsigned short(*)[8192])smem;  // [2][16KB] B tiles
    float* s2l = (float*)(smem + 32768);                            // 16KB
    unsigned short* Pb = (unsigned short*)(smem + 49152);           // 4KB P granules
    float* outl = (float*)smem;                                     // epi alias over W1buf
    __shared__ float Zp[2][4][16];
    int hop, strip;
    map384(blockIdx.x, hop, strip);
    const int i0 = strip * 32;
    const unsigned long long* Bk = (hop == 0) ? B1 : ((hop == 1) ? B2 : B3);
    unsigned short* hrm = h_rm + (size_t)hop * NN * HH;
    unsigned short* hcm = h_cm + (size_t)hop * NN * HH;
    const int t = threadIdx.x, w = t >> 6, lane = t & 63;
    const int wr = w >> 2, wc = w & 3, kg = lane >> 4, ar = lane & 15;
    // stage s2 (8 f32/thread)
    *reinterpret_cast<float4*>(&s2l[t * 8]) = *reinterpret_cast<const float4*>(&s2v[t * 8]);
    *reinterpret_cast<float4*>(&s2l[t * 8 + 4]) = *reinterpret_cast<const float4*>(&s2v[t * 8 + 4]);
    // per-lane row shifts for the 4 rows this lane exps (rows 16wr+4kg+ri)
    float s14[4], M4[4];
#pragma unroll
    for (int ri = 0; ri < 4; ++ri) {
        s14[ri] = s1v[i0 + 16 * wr + 4 * kg + ri];
        M4[ri] = lrelu(s14[ri] + s2mx[0]);
    }
    // tile stage: [d=128][8 c-granules], slot s holds source granule s^(d&7)
    auto stage = [&](int buf, int cn) {
#pragma unroll
        for (int j = 0; j < 2; ++j) {
            const int G = w * 128 + j * 64 + lane;
            const int d = G >> 3, cs = G & 7;
            gld16(&W1hTb[(size_t)d * NN + cn + ((cs ^ (d & 7)) << 3)],
                  &W1buf[buf][(w * 128 + j * 64) * 8]);
        }
    };
    stage(0, 0);
    f32x4 o0 = {0.f, 0.f, 0.f, 0.f}, o1 = {0.f, 0.f, 0.f, 0.f};
    f32x4 z4 = {0.f, 0.f, 0.f, 0.f};
    const int cw = 16 * wc + ar;  // this lane's column within each window
    __syncthreads();  // s2l + tile0 ready
    for (int ct = 0; ct < NT; ++ct) {
        const int p = ct & 1;
        if (ct < NT - 1) stage(p ^ 1, (ct + 1) * 64);
        unsigned long long bwv[4];
#pragma unroll
        for (int ri = 0; ri < 4; ++ri)
            bwv[ri] = Bk[(size_t)(i0 + 16 * wr + 4 * kg + ri) * WPR + ct];
        // masked exp of rank-1 e -> shared P granules (4 exp/lane, no duplication)
        const float s2val = s2l[ct * 64 + cw];
#pragma unroll
        for (int ri = 0; ri < 4; ++ri) {
            const float ev =
                ((bwv[ri] >> cw) & 1ull) ? __expf(lrelu(s14[ri] + s2val) - M4[ri]) : 0.f;
            z4[ri] += ev;
            const int kc = cw >> 5, kgp = (cw & 31) >> 3;
            const int lp = (kgp << 4) | (4 * kg + ri);
            Pb[((wr * 2 + kc) * 64 + lp) * 8 + (cw & 7)] = f2bf(ev);
        }
        // mid barrier WITHOUT vmcnt drain: staging loads stay in flight
        asm volatile("s_waitcnt lgkmcnt(0)\n\ts_barrier" ::: "memory");
        // PV from shared granules
#pragma unroll
        for (int kc = 0; kc < 2; ++kc) {
            const bf16x8 a = *reinterpret_cast<const bf16x8*>(
                &Pb[((wr * 2 + kc) * 64 + lane) * 8]);
            const int g = kc * 4 + kg;
            const int d0 = 32 * wc + ar, d1 = d0 + 16;
            const bf16x8 b0 = *reinterpret_cast<const bf16x8*>(
                &W1buf[p][(d0 * 8 + (g ^ (d0 & 7))) * 8]);
            const bf16x8 b1 = *reinterpret_cast<const bf16x8*>(
                &W1buf[p][(d1 * 8 + (g ^ (d1 & 7))) * 8]);
            o0 = MFMA(a, b0, o0);
            o1 = MFMA(a, b1, o1);
        }
        __syncthreads();  // frees P + buf p; drains ct+1 staging loads
    }
    // Z reduce over ar lanes, publish per-wc partials
#pragma unroll
    for (int ri = 0; ri < 4; ++ri) {
        z4[ri] += __shfl_xor(z4[ri], 1, 64);
        z4[ri] += __shfl_xor(z4[ri], 2, 64);
        z4[ri] += __shfl_xor(z4[ri], 4, 64);
        z4[ri] += __shfl_xor(z4[ri], 8, 64);
    }
    if (ar == 0) {
#pragma unroll
        for (int ri = 0; ri < 4; ++ri) Zp[wr][wc][4 * kg + ri] = z4[ri];
    }
    __syncthreads();
    // normalize into outl (aliases W1buf, safe post-barrier)
#pragma unroll
    for (int ri = 0; ri < 4; ++ri) {
        const int r16 = 4 * kg + ri;
        const int row = 16 * wr + r16;
        const float iz =
            1.f / (Zp[wr][0][r16] + Zp[wr][1][r16] + Zp[wr][2][r16] + Zp[wr][3][r16]);
        outl[row * 128 + 32 * wc + ar] = o0[ri] * iz;
        outl[row * 128 + 32 * wc + 16 + ar] = o1[ri] * iz;
    }
    __syncthreads();
    {   // h_rm + hnorm: thread t -> row t>>4, 8 dims
        const int row = t >> 4, l16 = t & 15;
        float nsum = 0.f;
        bf16x8 pk;
#pragma unroll
        for (int j = 0; j < 8; ++j) {
            float f = outl[row * 128 + l16 * 8 + j];
            nsum += f * f;
            pk[j] = (short)f2bf(f);
        }
        nsum += __shfl_xor(nsum, 1, 64);
        nsum += __shfl_xor(nsum, 2, 64);
        nsum += __shfl_xor(nsum, 4, 64);
        nsum += __shfl_xor(nsum, 8, 64);
        if (l16 == 0) hnorm[(size_t)hop * NN + i0 + row] = sqrtf(nsum);
        *reinterpret_cast<bf16x8*>(&hrm[(size_t)(i0 + row) * HH + l16 * 8]) = pk;
    }
    {   // h_cm transpose: thread t -> dim t>>2, rows (t&3)*8..
        const int d = t >> 2, r0 = (t & 3) * 8;
        bf16x8 v;
#pragma unroll
        for (int j = 0; j < 8; ++j) v[j] = (short)f2bf(outl[(r0 + j) * 128 + d]);
        *reinterpret_cast<bf16x8*>(&hcm[(size_t)d * NN + i0 + r0]) = v;
    }
}

// ---- hop pass B: S=h@W2h^T, fixed-shift masked softmax, O=P@h; staged pipeline ----
__global__ __launch_bounds__(512, 4) void k_hopB(const unsigned long long* __restrict__ B1,
                                                 const unsigned long long* __restrict__ B2,
                                                 const unsigned long long* __restrict__ B3,
                                                 const unsigned short* __restrict__ h_rm,
                                                 const unsigned short* __restrict__ W2hb,
                                                 const unsigned short* __restrict__ h_cm,
                                                 const float* __restrict__ hnorm,
                                                 const float* __restrict__ Mw,
                                                 unsigned short* __restrict__ accb) {
    __shared__ __align__(16) char smem[69632];
    unsigned short (*W2buf)[8192] = (unsigned short(*)[8192])smem;            // [2][16KB]
    unsigned short (*hTbuf)[8192] = (unsigned short(*)[8192])(smem + 32768);  // [2][16KB]
    unsigned short* Pb = (unsigned short*)(smem + 65536);                     // 4KB granules
    float* outl = (float*)smem;                                               // epi alias
    __shared__ float Zp[2][4][16];
    int hop, strip;
    map384(blockIdx.x, hop, strip);
    const int i0 = strip * 32;
    const unsigned long long* Bk = (hop == 0) ? B1 : ((hop == 1) ? B2 : B3);
    const unsigned short* hrm = h_rm + (size_t)hop * NN * HH;
    const unsigned short* hcm = h_cm + (size_t)hop * NN * HH;
    unsigned short* ab = accb + (size_t)hop * NN * HH;
    const int t = threadIdx.x, w = t >> 6, lane = t & 63;
    const int wr = w >> 2, wc = w & 3, kg = lane >> 4, ar = lane & 15;
    // A-frags for S: h rows i0+16wr+ar, K=128
    bf16x8 af[4];
#pragma unroll
    for (int ks = 0; ks < 4; ++ks)
        af[ks] = *reinterpret_cast<const bf16x8*>(
            &hrm[(size_t)(i0 + 16 * wr + ar) * HH + ks * 32 + kg * 8]);
    const float MwS = Mw[0];
    float hm4[4];
#pragma unroll
    for (int ri = 0; ri < 4; ++ri)
        hm4[ri] = hnorm[(size_t)hop * NN + i0 + 16 * wr + 4 * kg + ri] * MwS;
    // stage: W2 tile [col=64][16 k-granules], hT tile [d=128][8 c-granules]; swz sources
    auto stage = [&](int buf, int cn) {
#pragma unroll
        for (int j = 0; j < 2; ++j) {
            const int G = w * 128 + j * 64 + lane;
            const int col = G >> 4, s = G & 15;
            gld16(&W2hb[(size_t)(cn + col) * HH + ((s ^ (col & 7)) << 3)],
                  &W2buf[buf][(w * 128 + j * 64) * 8]);
            const int d = G >> 3, cs = G & 7;
            gld16(&hcm[(size_t)d * NN + cn + ((cs ^ (d & 7)) << 3)],
                  &hTbuf[buf][(w * 128 + j * 64) * 8]);
        }
    };
    stage(0, 0);
    f32x4 o0 = {0.f, 0.f, 0.f, 0.f}, o1 = {0.f, 0.f, 0.f, 0.f};
    f32x4 z4 = {0.f, 0.f, 0.f, 0.f};
    __syncthreads();
    for (int ct = 0; ct < NT; ++ct) {
        const int p = ct & 1;
        if (ct < NT - 1) stage(p ^ 1, (ct + 1) * 64);
        unsigned long long bwv[4];
#pragma unroll
        for (int ri = 0; ri < 4; ++ri)
            bwv[ri] = Bk[(size_t)(i0 + 16 * wr + 4 * kg + ri) * WPR + ct];
        // S: wave computes S[16 rows][16 cols of window]
        const int cw = 16 * wc + ar;
        f32x4 s = {0.f, 0.f, 0.f, 0.f};
#pragma unroll
        for (int ks = 0; ks < 4; ++ks) {
            const int g = ks * 4 + kg;
            const bf16x8 b = *reinterpret_cast<const bf16x8*>(
                &W2buf[p][(cw * 16 + (g ^ (cw & 7))) * 8]);
            s = MFMA(af[ks], b, s);
        }
        // masked exp -> P granules
#pragma unroll
        for (int ri = 0; ri < 4; ++ri) {
            const float ev = ((bwv[ri] >> cw) & 1ull) ? __expf(s[ri] - hm4[ri]) : 0.f;
            z4[ri] += ev;
            const int kc = cw >> 5, kgp = (cw & 31) >> 3;
            const int lp = (kgp << 4) | (4 * kg + ri);
            Pb[((wr * 2 + kc) * 64 + lp) * 8 + (cw & 7)] = f2bf(ev);
        }
        // mid barrier WITHOUT vmcnt drain: staging loads stay in flight
        asm volatile("s_waitcnt lgkmcnt(0)\n\ts_barrier" ::: "memory");
        // PV
#pragma unroll
        for (int kc = 0; kc < 2; ++kc) {
            const bf16x8 a = *reinterpret_cast<const bf16x8*>(
                &Pb[((wr * 2 + kc) * 64 + lane) * 8]);
            const int g = kc * 4 + kg;
            const int d0 = 32 * wc + ar, d1 = d0 + 16;
            const bf16x8 b0 = *reinterpret_cast<const bf16x8*>(
                &hTbuf[p][(d0 * 8 + (g ^ (d0 & 7))) * 8]);
            const bf16x8 b1 = *reinterpret_cast<const bf16x8*>(
                &hTbuf[p][(d1 * 8 + (g ^ (d1 & 7))) * 8]);
            o0 = MFMA(a, b0, o0);
            o1 = MFMA(a, b1, o1);
        }
        __syncthreads();  // frees P + buf p; drains ct+1 staging loads
    }
    // Z reduce over ar lanes, publish per-wc partials
#pragma unroll
    for (int ri = 0; ri < 4; ++ri) {
        z4[ri] += __shfl_xor(z4[ri], 1, 64);
        z4[ri] += __shfl_xor(z4[ri], 2, 64);
        z4[ri] += __shfl_xor(z4[ri], 4, 64);
        z4[ri] += __shfl_xor(z4[ri], 8, 64);
    }
    if (ar == 0) {
#pragma unroll
        for (int ri = 0; ri < 4; ++ri) Zp[wr][wc][4 * kg + ri] = z4[ri];
    }
    __syncthreads();
#pragma unroll
    for (int ri = 0; ri < 4; ++ri) {
        const int r16 = 4 * kg + ri;
        const int row = 16 * wr + r16;
        const float iz =
            1.f / (Zp[wr][0][r16] + Zp[wr][1][r16] + Zp[wr][2][r16] + Zp[wr][3][r16]);
        outl[row * 128 + 32 * wc + ar] = o0[ri] * iz;
        outl[row * 128 + 32 * wc + 16 + ar] = o1[ri] * iz;
    }
    __syncthreads();
    {   // coalesced bf16 write
        const int row = t >> 4, l16 = t & 15;
        bf16x8 pk;
#pragma unroll
        for (int j = 0; j < 8; ++j) pk[j] = (short)f2bf(outl[row * 128 + l16 * 8 + j]);
        *reinterpret_cast<bf16x8*>(&ab[(size_t)(i0 + row) * HH + l16 * 8]) = pk;
    }
}

// ---- finalize: out = [U_l + sum(acc_k) ; sum(acc_k)] ----
__global__ void k_fin(const float* __restrict__ Ul, const unsigned short* __restrict__ accb,
                      float* __restrict__ out) {
    int idx = blockIdx.x * 256 + threadIdx.x;
    float a = bf2f(accb[idx]) + bf2f(accb[NN * HH + idx]) + bf2f(accb[2 * NN * HH + idx]);
    out[idx] = Ul[idx] + a;
    out[NN * HH + idx] = a;
}

extern "C" void kernel_launch(void* const* d_in, const int* in_sizes, int n_in,
                              void* d_out, int out_size, void* d_ws, size_t ws_size,
                              hipStream_t stream) {
    const float* X   = (const float*)d_in[0];
    const float* A   = (const float*)d_in[1];
    const float* Ul  = (const float*)d_in[2];
    const float* W1w = (const float*)d_in[3];
    const float* W2w = (const float*)d_in[4];
    const float* r   = (const float*)d_in[5];
    float* out = (float*)d_out;

    char* ws = (char*)d_ws;
    // Region plan (17 MB total), unchanged from R11.
    float* W1h            = (float*)(ws);
    float* hnorm          = (float*)(ws);
    float* Mw             = (float*)(ws + (48 << 10));
    unsigned short* accb  = (unsigned short*)(ws + (64 << 10));
    float* s1             = (float*)(ws + (2ull << 20));
    float* s2             = (float*)(ws + (2ull << 20) + (64 << 10));
    float* s2mx           = (float*)(ws + (2ull << 20) + (128 << 10));
    float* wnorm          = (float*)(ws + (2ull << 20) + (192 << 10));
    unsigned short* W1hTb = (unsigned short*)(ws + (3ull << 20));
    unsigned short* W2hb  = (unsigned short*)(ws + (4ull << 20));
    unsigned short* h_rm  = (unsigned short*)(ws + (5ull << 20));
    unsigned short* h_cm  = (unsigned short*)(ws + (8ull << 20));
    unsigned long long* B1 = (unsigned long long*)(ws + (11ull << 20));
    unsigned long long* B2 = (unsigned long long*)(ws + (13ull << 20));
    unsigned long long* B3 = (unsigned long long*)(ws + (15ull << 20));

    k_xw<<<NN / 16, 256, 0, stream>>>(X, W1w, W2w, W1h, W1hTb, W2hb);
    k_s<<<NN / 256, 256, 0, stream>>>(W1h, r, s1, s2);
    k_gmax<<<1, 256, 0, stream>>>(s2, s2mx);
    k_wn<<<NN / 16, 256, 0, stream>>>(W2hb, wnorm);
    k_gmax<<<1, 256, 0, stream>>>(wnorm, Mw);
    k_b1<<<NN / 4, 256, 0, stream>>>(A, B1);
    k_boolmm<<<NN / 4, 256, 0, stream>>>(B1, B1, B2);
    k_boolmm<<<NN / 4, 256, 0, stream>>>(B1, B2, B3);

    k_hopA<<<3 * (NN / 32), 512, 0, stream>>>(B1, B2, B3, s1, s2, s2mx, W1hTb,
                                              h_rm, h_cm, hnorm);
    k_hopB<<<3 * (NN / 32), 512, 0, stream>>>(B1, B2, B3, h_rm, W2hb, h_cm,
                                              hnorm, Mw, accb);
    k_fin<<<NN * HH / 256, 256, 0, stream>>>(Ul, accb, out);
}

// Round 13
// 256.113 us; speedup vs baseline: 1.5362x; 1.0857x over previous
//
#include <hip/hip_runtime.h>
#include <hip/hip_bf16.h>

// LSDAN: 3-hop masked graph attention, N=4096, IN_F=256, H=128.
//  - masks of A^k via boolean bitset reachability (A is 0/1 with self-loops).
//  - e is rank-1: e[i][j]=lrelu(s1[i]+s2[j]); hopA shift M=lrelu(s1+gmax(s2)) (valid UB).
//  - hopB: fixed per-row shift M_i=||h_i||*max_j||W2h_j|| >= rowmax (Cauchy-Schwarz).
//  - Staged pipeline (R11/R12): B-operands via global_load_lds(16B) into double-buffered
//    LDS tiles (pre-swizzled SOURCE + swizzled read, rule #21). Mid-iter barrier is
//    raw s_waitcnt lgkmcnt(0)+s_barrier (staging vmcnt stays in flight across it).
//  - THIS ROUND: (a) kc-split PV roles — waves are (wr,wc) for S/exp but (kc,wc) for
//    PV, so each hT/W1hT B-fragment is read ONCE (PV LDS reads 48->32KB/iter); kc
//    partials combined once at kernel end via f32 LDS reduce. (b) bitset prefetch one
//    window ahead (removes per-iter L2/L3 latency from the exp critical path).

#define NN 4096
#define INF 256
#define HH 128
#define WPR 64
#define ALPHA_S 0.2f
#define NT 64

typedef short bf16x8 __attribute__((ext_vector_type(8)));
typedef float f32x4 __attribute__((ext_vector_type(4)));

#define MFMA(a, b, c) __builtin_amdgcn_mfma_f32_16x16x32_bf16(a, b, c, 0, 0, 0)

__device__ __forceinline__ float lrelu(float x) { return x > 0.f ? x : ALPHA_S * x; }
__device__ __forceinline__ unsigned short f2bf(float x) {
    __hip_bfloat16 h = __float2bfloat16(x);
    return *reinterpret_cast<unsigned short*>(&h);
}
__device__ __forceinline__ float bf2f(unsigned short u) {
    return __uint_as_float(((unsigned int)u) << 16);
}
// async global->LDS 16B: per-lane global src, wave-uniform LDS base (+lane*16 by HW)
__device__ __forceinline__ void gld16(const void* g, void* l) {
    __builtin_amdgcn_global_load_lds(
        (const __attribute__((address_space(1))) unsigned int*)g,
        (__attribute__((address_space(3))) unsigned int*)l, 16, 0, 0);
}

// XCD-affine (hop,strip) map for 384 blocks: r=x&7 ~ XCD, k=x>>3 in [0,48).
__device__ __forceinline__ void map384(int x, int& hop, int& strip) {
    const int r = x & 7, k = x >> 3;
    if (r == 0) { hop = 0; strip = k; }
    else if (r == 1) { hop = 0; strip = 48 + k; }
    else if (r == 2) { if (k < 32) { hop = 0; strip = 96 + k; } else { hop = 1; strip = k - 32; } }
    else if (r == 3) { hop = 1; strip = 16 + k; }
    else if (r == 4) { hop = 1; strip = 64 + k; }
    else if (r == 5) { if (k < 16) { hop = 1; strip = 112 + k; } else { hop = 2; strip = k - 16; } }
    else if (r == 6) { hop = 2; strip = 32 + k; }
    else { hop = 2; strip = 80 + k; }
}

// ---- W1h = X@W1^T (f32 + bf16-transposed), W2h = X@W2^T (bf16 row-major) ----
__global__ __launch_bounds__(256) void k_xw(const float* __restrict__ X,
                                            const float* __restrict__ W1,
                                            const float* __restrict__ W2,
                                            float* __restrict__ W1h,
                                            unsigned short* __restrict__ W1hTb,
                                            unsigned short* __restrict__ W2hb) {
    __shared__ float xs[16 * INF];
    const int row0 = blockIdx.x * 16;
    const int t = threadIdx.x;
    for (int v = t; v < 16 * INF; v += 256) xs[v] = X[(size_t)row0 * INF + v];
    __syncthreads();
    const int c = t;
    const float* W = (c < HH) ? (W1 + (size_t)c * INF) : (W2 + (size_t)(c - HH) * INF);
    float acc[16];
#pragma unroll
    for (int r = 0; r < 16; ++r) acc[r] = 0.f;
    for (int k = 0; k < INF; ++k) {
        float wv = W[k];
#pragma unroll
        for (int r = 0; r < 16; ++r) acc[r] += xs[r * INF + k] * wv;
    }
    if (c < HH) {
        for (int r = 0; r < 16; ++r) {
            W1h[(size_t)(row0 + r) * HH + c] = acc[r];
            W1hTb[(size_t)c * NN + row0 + r] = f2bf(acc[r]);
        }
    } else {
        const int cc = c - HH;
        for (int r = 0; r < 16; ++r) W2hb[(size_t)(row0 + r) * HH + cc] = f2bf(acc[r]);
    }
}

// ---- s1 = W1h @ r[:H], s2 = W1h @ r[H:] ----
__global__ void k_s(const float* __restrict__ W1h, const float* __restrict__ r,
                    float* __restrict__ s1, float* __restrict__ s2) {
    int i = blockIdx.x * blockDim.x + threadIdx.x;
    if (i >= NN) return;
    float a = 0.f, b = 0.f;
    for (int h = 0; h < HH; ++h) {
        float v = W1h[(size_t)i * HH + h];
        a += v * r[h];
        b += v * r[HH + h];
    }
    s1[i] = a;
    s2[i] = b;
}

// ---- global max of 4096 floats ----
__global__ void k_gmax(const float* __restrict__ in, float* __restrict__ out) {
    __shared__ float red[256];
    const int t = threadIdx.x;
    float m = -3e38f;
    for (int i = t; i < NN; i += 256) m = fmaxf(m, in[i]);
    red[t] = m;
    __syncthreads();
    for (int off = 128; off; off >>= 1) {
        if (t < off) red[t] = fmaxf(red[t], red[t + off]);
        __syncthreads();
    }
    if (t == 0) out[0] = red[0];
}

// ---- W2h row norms ----
__global__ void k_wn(const unsigned short* __restrict__ W2hb, float* __restrict__ wnorm) {
    const int t = threadIdx.x;
    const int row = blockIdx.x * 16 + (t >> 4);
    const int sub = t & 15;
    bf16x8 v = *reinterpret_cast<const bf16x8*>(&W2hb[(size_t)row * HH + sub * 8]);
    float s = 0.f;
#pragma unroll
    for (int j = 0; j < 8; ++j) { float f = bf2f((unsigned short)v[j]); s += f * f; }
    s += __shfl_xor(s, 1, 64); s += __shfl_xor(s, 2, 64);
    s += __shfl_xor(s, 4, 64); s += __shfl_xor(s, 8, 64);
    if (sub == 0) wnorm[row] = sqrtf(s);
}

// ---- B1[i] bitset from A row i ----
__global__ void k_b1(const float* __restrict__ A, unsigned long long* __restrict__ B1) {
    const int wave = threadIdx.x >> 6;
    const int lane = threadIdx.x & 63;
    const int i = blockIdx.x * 4 + wave;
    for (int w = 0; w < WPR; ++w) {
        float a = A[(size_t)i * NN + w * 64 + lane];
        unsigned long long m = __ballot(a != 0.0f);
        if (lane == 0) B1[(size_t)i * WPR + w] = m;
    }
}

// ---- boolean matmul for reachability ----
__global__ void k_boolmm(const unsigned long long* __restrict__ srcbits,
                         const unsigned long long* __restrict__ mat,
                         unsigned long long* __restrict__ out) {
    const int wave = threadIdx.x >> 6;
    const int lane = threadIdx.x & 63;
    const int i = blockIdx.x * 4 + wave;
    unsigned long long myword = srcbits[(size_t)i * WPR + lane];
    unsigned long long acc = 0ull;
    for (int w = 0; w < WPR; ++w) {
        unsigned long long bits = __shfl(myword, w, 64);
        while (bits) {
            int b = __builtin_ctzll(bits);
            bits &= bits - 1;
            acc |= mat[(size_t)(w * 64 + b) * WPR + lane];
        }
    }
    out[(size_t)i * WPR + lane] = acc;
}

// ---- hop pass A: h = softmax_masked(rank1 e) @ W1h; staged, kc-split PV ----
__global__ __launch_bounds__(512, 4) void k_hopA(const unsigned long long* __restrict__ B1,
                                                 const unsigned long long* __restrict__ B2,
                                                 const unsigned long long* __restrict__ B3,
                                                 const float* __restrict__ s1v,
                                                 const float* __restrict__ s2v,
                                                 const float* __restrict__ s2mx,
                                                 const unsigned short* __restrict__ W1hTb,
                                                 unsigned short* __restrict__ h_rm,
                                                 unsigned short* __restrict__ h_cm,
                                                 float* __restrict__ hnorm) {
    __shared__ __align__(16) char smem[53248];
    unsigned short (*W1buf)[8192] = (unsigned short(*)[8192])smem;  // [2][16KB] B tiles
    float* s2l = (float*)(smem + 32768);                            // 16KB
    unsigned short* Pb = (unsigned short*)(smem + 49152);           // 4KB P granules
    float* outl = (float*)smem;                                     // epi alias (16KB f32)
    __shared__ float Zp[2][4][16];
    int hop, strip;
    map384(blockIdx.x, hop, strip);
    const int i0 = strip * 32;
    const unsigned long long* Bk = (hop == 0) ? B1 : ((hop == 1) ? B2 : B3);
    unsigned short* hrm = h_rm + (size_t)hop * NN * HH;
    unsigned short* hcm = h_cm + (size_t)hop * NN * HH;
    const int t = threadIdx.x, w = t >> 6, lane = t & 63;
    const int wrS = w >> 2, wcS = w & 3;   // S/exp-phase role
    const int kcP = w >> 2, wcP = w & 3;   // PV-phase role
    const int kg = lane >> 4, ar = lane & 15;
    // stage s2 (8 f32/thread)
    *reinterpret_cast<float4*>(&s2l[t * 8]) = *reinterpret_cast<const float4*>(&s2v[t * 8]);
    *reinterpret_cast<float4*>(&s2l[t * 8 + 4]) = *reinterpret_cast<const float4*>(&s2v[t * 8 + 4]);
    // per-lane row shifts for the 4 rows this lane exps (rows 16wrS+4kg+ri)
    float s14[4], M4[4];
#pragma unroll
    for (int ri = 0; ri < 4; ++ri) {
        s14[ri] = s1v[i0 + 16 * wrS + 4 * kg + ri];
        M4[ri] = lrelu(s14[ri] + s2mx[0]);
    }
    // tile stage: [d=128][8 c-granules], slot s holds source granule s^(d&7)
    auto stage = [&](int buf, int cn) {
#pragma unroll
        for (int j = 0; j < 2; ++j) {
            const int G = w * 128 + j * 64 + lane;
            const int d = G >> 3, cs = G & 7;
            gld16(&W1hTb[(size_t)d * NN + cn + ((cs ^ (d & 7)) << 3)],
                  &W1buf[buf][(w * 128 + j * 64) * 8]);
        }
    };
    stage(0, 0);
    f32x4 o00 = {0.f, 0.f, 0.f, 0.f}, o01 = {0.f, 0.f, 0.f, 0.f};
    f32x4 o10 = {0.f, 0.f, 0.f, 0.f}, o11 = {0.f, 0.f, 0.f, 0.f};
    f32x4 z4 = {0.f, 0.f, 0.f, 0.f};
    const int cw = 16 * wcS + ar;  // this lane's column within each window (S role)
    // prefetch bitsets for ct=0
    unsigned long long bwv[4];
#pragma unroll
    for (int ri = 0; ri < 4; ++ri)
        bwv[ri] = Bk[(size_t)(i0 + 16 * wrS + 4 * kg + ri) * WPR];
    __syncthreads();  // s2l + tile0 ready
    for (int ct = 0; ct < NT; ++ct) {
        const int p = ct & 1;
        if (ct < NT - 1) stage(p ^ 1, (ct + 1) * 64);
        // prefetch next-iter bitsets (consumed next iter -> full-iter latency cover)
        unsigned long long nbw[4];
        {
            const int cn = (ct + 1 < NT) ? ct + 1 : NT - 1;
#pragma unroll
            for (int ri = 0; ri < 4; ++ri)
                nbw[ri] = Bk[(size_t)(i0 + 16 * wrS + 4 * kg + ri) * WPR + cn];
        }
        // masked exp of rank-1 e -> shared P granules (4 exp/lane, no duplication)
        const float s2val = s2l[ct * 64 + cw];
#pragma unroll
        for (int ri = 0; ri < 4; ++ri) {
            const float ev =
                ((bwv[ri] >> cw) & 1ull) ? __expf(lrelu(s14[ri] + s2val) - M4[ri]) : 0.f;
            z4[ri] += ev;
            const int kc = cw >> 5, kgp = (cw & 31) >> 3;
            const int lp = (kgp << 4) | (4 * kg + ri);
            Pb[((wrS * 2 + kc) * 64 + lp) * 8 + (cw & 7)] = f2bf(ev);
        }
#pragma unroll
        for (int ri = 0; ri < 4; ++ri) bwv[ri] = nbw[ri];
        // mid barrier WITHOUT vmcnt drain: staging loads stay in flight
        asm volatile("s_waitcnt lgkmcnt(0)\n\ts_barrier" ::: "memory");
        // PV (kc-split): this wave covers its kc for ALL 32 rows, dims 32wcP..+31
        {
            const bf16x8 a0 = *reinterpret_cast<const bf16x8*>(&Pb[(kcP * 64 + lane) * 8]);
            const bf16x8 a1 =
                *reinterpret_cast<const bf16x8*>(&Pb[((2 + kcP) * 64 + lane) * 8]);
            const int g = kcP * 4 + kg;
            const int d0 = 32 * wcP + ar, d1 = d0 + 16;
            const bf16x8 b0 = *reinterpret_cast<const bf16x8*>(
                &W1buf[p][(d0 * 8 + (g ^ (d0 & 7))) * 8]);
            const bf16x8 b1 = *reinterpret_cast<const bf16x8*>(
                &W1buf[p][(d1 * 8 + (g ^ (d1 & 7))) * 8]);
            o00 = MFMA(a0, b0, o00);
            o01 = MFMA(a0, b1, o01);
            o10 = MFMA(a1, b0, o10);
            o11 = MFMA(a1, b1, o11);
        }
        __syncthreads();  // frees P + buf p; drains staging loads
    }
    // Z reduce over ar lanes, publish per-wc partials (S roles)
#pragma unroll
    for (int ri = 0; ri < 4; ++ri) {
        z4[ri] += __shfl_xor(z4[ri], 1, 64);
        z4[ri] += __shfl_xor(z4[ri], 2, 64);
        z4[ri] += __shfl_xor(z4[ri], 4, 64);
        z4[ri] += __shfl_xor(z4[ri], 8, 64);
    }
    if (ar == 0) {
#pragma unroll
        for (int ri = 0; ri < 4; ++ri) Zp[wrS][wcS][4 * kg + ri] = z4[ri];
    }
    __syncthreads();  // Zp visible; smem becomes outl
    // combine kc partials: kc=0 writes, kc=1 adds
    {
        const int d0 = 32 * wcP + ar, d1 = d0 + 16;
        if (kcP == 0) {
#pragma unroll
            for (int ri = 0; ri < 4; ++ri) {
                outl[(4 * kg + ri) * 128 + d0] = o00[ri];
                outl[(4 * kg + ri) * 128 + d1] = o01[ri];
                outl[(16 + 4 * kg + ri) * 128 + d0] = o10[ri];
                outl[(16 + 4 * kg + ri) * 128 + d1] = o11[ri];
            }
        }
        __syncthreads();
        if (kcP == 1) {
#pragma unroll
            for (int ri = 0; ri < 4; ++ri) {
                outl[(4 * kg + ri) * 128 + d0] += o00[ri];
                outl[(4 * kg + ri) * 128 + d1] += o01[ri];
                outl[(16 + 4 * kg + ri) * 128 + d0] += o10[ri];
                outl[(16 + 4 * kg + ri) * 128 + d1] += o11[ri];
            }
        }
        __syncthreads();
    }
    {   // normalize in place + h_rm + hnorm: thread t -> row t>>4, 8 dims
        const int row = t >> 4, l16 = t & 15;
        const int r16 = row & 15, rh = row >> 4;
        const float z = Zp[rh][0][r16] + Zp[rh][1][r16] + Zp[rh][2][r16] + Zp[rh][3][r16];
        const float iz = 1.f / z;
        float nsum = 0.f;
        bf16x8 pk;
#pragma unroll
        for (int j = 0; j < 8; ++j) {
            float f = outl[row * 128 + l16 * 8 + j] * iz;
            outl[row * 128 + l16 * 8 + j] = f;  // write back normalized for transpose
            nsum += f * f;
            pk[j] = (short)f2bf(f);
        }
        nsum += __shfl_xor(nsum, 1, 64);
        nsum += __shfl_xor(nsum, 2, 64);
        nsum += __shfl_xor(nsum, 4, 64);
        nsum += __shfl_xor(nsum, 8, 64);
        if (l16 == 0) hnorm[(size_t)hop * NN + i0 + row] = sqrtf(nsum);
        *reinterpret_cast<bf16x8*>(&hrm[(size_t)(i0 + row) * HH + l16 * 8]) = pk;
    }
    __syncthreads();
    {   // h_cm transpose: thread t -> dim t>>2, rows (t&3)*8..
        const int d = t >> 2, r0 = (t & 3) * 8;
        bf16x8 v;
#pragma unroll
        for (int j = 0; j < 8; ++j) v[j] = (short)f2bf(outl[(r0 + j) * 128 + d]);
        *reinterpret_cast<bf16x8*>(&hcm[(size_t)d * NN + i0 + r0]) = v;
    }
}

// ---- hop pass B: S=h@W2h^T, fixed-shift softmax, O=P@h; staged, kc-split PV ----
__global__ __launch_bounds__(512, 4) void k_hopB(const unsigned long long* __restrict__ B1,
                                                 const unsigned long long* __restrict__ B2,
                                                 const unsigned long long* __restrict__ B3,
                                                 const unsigned short* __restrict__ h_rm,
                                                 const unsigned short* __restrict__ W2hb,
                                                 const unsigned short* __restrict__ h_cm,
                                                 const float* __restrict__ hnorm,
                                                 const float* __restrict__ Mw,
                                                 unsigned short* __restrict__ accb) {
    __shared__ __align__(16) char smem[69632];
    unsigned short (*W2buf)[8192] = (unsigned short(*)[8192])smem;            // [2][16KB]
    unsigned short (*hTbuf)[8192] = (unsigned short(*)[8192])(smem + 32768);  // [2][16KB]
    unsigned short* Pb = (unsigned short*)(smem + 65536);                     // 4KB granules
    float* outl = (float*)smem;                                               // epi alias
    __shared__ float Zp[2][4][16];
    int hop, strip;
    map384(blockIdx.x, hop, strip);
    const int i0 = strip * 32;
    const unsigned long long* Bk = (hop == 0) ? B1 : ((hop == 1) ? B2 : B3);
    const unsigned short* hrm = h_rm + (size_t)hop * NN * HH;
    const unsigned short* hcm = h_cm + (size_t)hop * NN * HH;
    unsigned short* ab = accb + (size_t)hop * NN * HH;
    const int t = threadIdx.x, w = t >> 6, lane = t & 63;
    const int wrS = w >> 2, wcS = w & 3;   // S/exp-phase role
    const int kcP = w >> 2, wcP = w & 3;   // PV-phase role
    const int kg = lane >> 4, ar = lane & 15;
    // A-frags for S: h rows i0+16wrS+ar, K=128
    bf16x8 af[4];
#pragma unroll
    for (int ks = 0; ks < 4; ++ks)
        af[ks] = *reinterpret_cast<const bf16x8*>(
            &hrm[(size_t)(i0 + 16 * wrS + ar) * HH + ks * 32 + kg * 8]);
    const float MwS = Mw[0];
    float hm4[4];
#pragma unroll
    for (int ri = 0; ri < 4; ++ri)
        hm4[ri] = hnorm[(size_t)hop * NN + i0 + 16 * wrS + 4 * kg + ri] * MwS;
    // stage: W2 tile [col=64][16 k-granules], hT tile [d=128][8 c-granules]; swz sources
    auto stage = [&](int buf, int cn) {
#pragma unroll
        for (int j = 0; j < 2; ++j) {
            const int G = w * 128 + j * 64 + lane;
            const int col = G >> 4, s = G & 15;
            gld16(&W2hb[(size_t)(cn + col) * HH + ((s ^ (col & 7)) << 3)],
                  &W2buf[buf][(w * 128 + j * 64) * 8]);
            const int d = G >> 3, cs = G & 7;
            gld16(&hcm[(size_t)d * NN + cn + ((cs ^ (d & 7)) << 3)],
                  &hTbuf[buf][(w * 128 + j * 64) * 8]);
        }
    };
    stage(0, 0);
    f32x4 o00 = {0.f, 0.f, 0.f, 0.f}, o01 = {0.f, 0.f, 0.f, 0.f};
    f32x4 o10 = {0.f, 0.f, 0.f, 0.f}, o11 = {0.f, 0.f, 0.f, 0.f};
    f32x4 z4 = {0.f, 0.f, 0.f, 0.f};
    const int cw = 16 * wcS + ar;
    // prefetch bitsets for ct=0
    unsigned long long bwv[4];
#pragma unroll
    for (int ri = 0; ri < 4; ++ri)
        bwv[ri] = Bk[(size_t)(i0 + 16 * wrS + 4 * kg + ri) * WPR];
    __syncthreads();
    for (int ct = 0; ct < NT; ++ct) {
        const int p = ct & 1;
        if (ct < NT - 1) stage(p ^ 1, (ct + 1) * 64);
        // prefetch next-iter bitsets
        unsigned long long nbw[4];
        {
            const int cn = (ct + 1 < NT) ? ct + 1 : NT - 1;
#pragma unroll
            for (int ri = 0; ri < 4; ++ri)
                nbw[ri] = Bk[(size_t)(i0 + 16 * wrS + 4 * kg + ri) * WPR + cn];
        }
        // S: wave computes S[16 rows][16 cols of window]
        f32x4 s = {0.f, 0.f, 0.f, 0.f};
#pragma unroll
        for (int ks = 0; ks < 4; ++ks) {
            const int g = ks * 4 + kg;
            const bf16x8 b = *reinterpret_cast<const bf16x8*>(
                &W2buf[p][(cw * 16 + (g ^ (cw & 7))) * 8]);
            s = MFMA(af[ks], b, s);
        }
        // masked exp -> P granules
#pragma unroll
        for (int ri = 0; ri < 4; ++ri) {
            const float ev = ((bwv[ri] >> cw) & 1ull) ? __expf(s[ri] - hm4[ri]) : 0.f;
            z4[ri] += ev;
            const int kc = cw >> 5, kgp = (cw & 31) >> 3;
            const int lp = (kgp << 4) | (4 * kg + ri);
            Pb[((wrS * 2 + kc) * 64 + lp) * 8 + (cw & 7)] = f2bf(ev);
        }
#pragma unroll
        for (int ri = 0; ri < 4; ++ri) bwv[ri] = nbw[ri];
        // mid barrier WITHOUT vmcnt drain: staging loads stay in flight
        asm volatile("s_waitcnt lgkmcnt(0)\n\ts_barrier" ::: "memory");
        // PV (kc-split): wave covers its kc for ALL 32 rows, dims 32wcP..+31
        {
            const bf16x8 a0 = *reinterpret_cast<const bf16x8*>(&Pb[(kcP * 64 + lane) * 8]);
            const bf16x8 a1 =
                *reinterpret_cast<const bf16x8*>(&Pb[((2 + kcP) * 64 + lane) * 8]);
            const int g = kcP * 4 + kg;
            const int d0 = 32 * wcP + ar, d1 = d0 + 16;
            const bf16x8 b0 = *reinterpret_cast<const bf16x8*>(
                &hTbuf[p][(d0 * 8 + (g ^ (d0 & 7))) * 8]);
            const bf16x8 b1 = *reinterpret_cast<const bf16x8*>(
                &hTbuf[p][(d1 * 8 + (g ^ (d1 & 7))) * 8]);
            o00 = MFMA(a0, b0, o00);
            o01 = MFMA(a0, b1, o01);
            o10 = MFMA(a1, b0, o10);
            o11 = MFMA(a1, b1, o11);
        }
        __syncthreads();  // frees P + buf p; drains staging loads
    }
    // Z reduce over ar lanes, publish per-wc partials (S roles)
#pragma unroll
    for (int ri = 0; ri < 4; ++ri) {
        z4[ri] += __shfl_xor(z4[ri], 1, 64);
        z4[ri] += __shfl_xor(z4[ri], 2, 64);
        z4[ri] += __shfl_xor(z4[ri], 4, 64);
        z4[ri] += __shfl_xor(z4[ri], 8, 64);
    }
    if (ar == 0) {
#pragma unroll
        for (int ri = 0; ri < 4; ++ri) Zp[wrS][wcS][4 * kg + ri] = z4[ri];
    }
    __syncthreads();  // Zp visible; smem becomes outl
    // combine kc partials
    {
        const int d0 = 32 * wcP + ar, d1 = d0 + 16;
        if (kcP == 0) {
#pragma unroll
            for (int ri = 0; ri < 4; ++ri) {
                outl[(4 * kg + ri) * 128 + d0] = o00[ri];
                outl[(4 * kg + ri) * 128 + d1] = o01[ri];
                outl[(16 + 4 * kg + ri) * 128 + d0] = o10[ri];
                outl[(16 + 4 * kg + ri) * 128 + d1] = o11[ri];
            }
        }
        __syncthreads();
        if (kcP == 1) {
#pragma unroll
            for (int ri = 0; ri < 4; ++ri) {
                outl[(4 * kg + ri) * 128 + d0] += o00[ri];
                outl[(4 * kg + ri) * 128 + d1] += o01[ri];
                outl[(16 + 4 * kg + ri) * 128 + d0] += o10[ri];
                outl[(16 + 4 * kg + ri) * 128 + d1] += o11[ri];
            }
        }
        __syncthreads();
    }
    {   // normalize + coalesced bf16 write
        const int row = t >> 4, l16 = t & 15;
        const int r16 = row & 15, rh = row >> 4;
        const float z = Zp[rh][0][r16] + Zp[rh][1][r16] + Zp[rh][2][r16] + Zp[rh][3][r16];
        const float iz = 1.f / z;
        bf16x8 pk;
#pragma unroll
        for (int j = 0; j < 8; ++j)
            pk[j] = (short)f2bf(outl[row * 128 + l16 * 8 + j] * iz);
        *reinterpret_cast<bf16x8*>(&ab[(size_t)(i0 + row) * HH + l16 * 8]) = pk;
    }
}

// ---- finalize: out = [U_l + sum(acc_k) ; sum(acc_k)] ----
__global__ void k_fin(const float* __restrict__ Ul, const unsigned short* __restrict__ accb,
                      float* __restrict__ out) {
    int idx = blockIdx.x * 256 + threadIdx.x;
    float a = bf2f(accb[idx]) + bf2f(accb[NN * HH + idx]) + bf2f(accb[2 * NN * HH + idx]);
    out[idx] = Ul[idx] + a;
    out[NN * HH + idx] = a;
}

extern "C" void kernel_launch(void* const* d_in, const int* in_sizes, int n_in,
                              void* d_out, int out_size, void* d_ws, size_t ws_size,
                              hipStream_t stream) {
    const float* X   = (const float*)d_in[0];
    const float* A   = (const float*)d_in[1];
    const float* Ul  = (const float*)d_in[2];
    const float* W1w = (const float*)d_in[3];
    const float* W2w = (const float*)d_in[4];
    const float* r   = (const float*)d_in[5];
    float* out = (float*)d_out;

    char* ws = (char*)d_ws;
    // Region plan (17 MB total), unchanged from R12.
    float* W1h            = (float*)(ws);
    float* hnorm          = (float*)(ws);
    float* Mw             = (float*)(ws + (48 << 10));
    unsigned short* accb  = (unsigned short*)(ws + (64 << 10));
    float* s1             = (float*)(ws + (2ull << 20));
    float* s2             = (float*)(ws + (2ull << 20) + (64 << 10));
    float* s2mx           = (float*)(ws + (2ull << 20) + (128 << 10));
    float* wnorm          = (float*)(ws + (2ull << 20) + (192 << 10));
    unsigned short* W1hTb = (unsigned short*)(ws + (3ull << 20));
    unsigned short* W2hb  = (unsigned short*)(ws + (4ull << 20));
    unsigned short* h_rm  = (unsigned short*)(ws + (5ull << 20));
    unsigned short* h_cm  = (unsigned short*)(ws + (8ull << 20));
    unsigned long long* B1 = (unsigned long long*)(ws + (11ull << 20));
    unsigned long long* B2 = (unsigned long long*)(ws + (13ull << 20));
    unsigned long long* B3 = (unsigned long long*)(ws + (15ull << 20));

    k_xw<<<NN / 16, 256, 0, stream>>>(X, W1w, W2w, W1h, W1hTb, W2hb);
    k_s<<<NN / 256, 256, 0, stream>>>(W1h, r, s1, s2);
    k_gmax<<<1, 256, 0, stream>>>(s2, s2mx);
    k_wn<<<NN / 16, 256, 0, stream>>>(W2hb, wnorm);
    k_gmax<<<1, 256, 0, stream>>>(wnorm, Mw);
    k_b1<<<NN / 4, 256, 0, stream>>>(A, B1);
    k_boolmm<<<NN / 4, 256, 0, stream>>>(B1, B1, B2);
    k_boolmm<<<NN / 4, 256, 0, stream>>>(B1, B2, B3);

    k_hopA<<<3 * (NN / 32), 512, 0, stream>>>(B1, B2, B3, s1, s2, s2mx, W1hTb,
                                              h_rm, h_cm, hnorm);
    k_hopB<<<3 * (NN / 32), 512, 0, stream>>>(B1, B2, B3, h_rm, W2hb, h_cm,
                                              hnorm, Mw, accb);
    k_fin<<<NN * HH / 256, 256, 0, stream>>>(Ul, accb, out);
}